// Round 1
// baseline (138.426 us; speedup 1.0000x reference)
//
#include <hip/hip_runtime.h>

typedef __attribute__((ext_vector_type(8))) short bf16x8;
typedef __attribute__((ext_vector_type(4))) float f32x4;

#define M_TOT 6400   // 80*80 flattened spatial positions
#define C_TOT 256    // channels (K of the GEMM)
#define BM 128
#define BN 128
#define BK 32

// f32 -> bf16 round-to-nearest-even (bit math; inputs are finite normals)
__device__ __forceinline__ short f2bf(float f) {
    unsigned u = __float_as_uint(f);
    u = (u + 0x7fffu + ((u >> 16) & 1u)) >> 16;
    return (short)u;
}

// corr = A * B^T / 256 written to out; penalty[m] += sum_n corr[m,n]^2 (atomic)
__global__ __launch_bounds__(256) void corr_gemm(const float* __restrict__ A,
                                                 const float* __restrict__ Bm,
                                                 float* __restrict__ out,
                                                 float* __restrict__ penalty)
{
    __shared__ short As[BM * BK];   // 8 KB, XOR-swizzled 16B slots
    __shared__ short Bs[BN * BK];   // 8 KB

    const int tid  = threadIdx.x;
    const int lane = tid & 63;
    const int wave = tid >> 6;           // 4 waves, 2x2 over the 128x128 tile
    const int wr   = wave >> 1;
    const int wc   = wave & 1;
    const int m0   = blockIdx.y * BM;
    const int n0   = blockIdx.x * BN;

    const int g_rd = lane >> 4;          // k-slot (8 bf16 each) this lane reads
    const int rl   = lane & 15;

    f32x4 acc[4][4] = {};

    for (int k0 = 0; k0 < C_TOT; k0 += BK) {
        // ---- stage A,B 128x32 tiles: global f32 -> bf16 -> LDS (swizzled) ----
        #pragma unroll
        for (int half = 0; half < 2; ++half) {
            const int cc = tid + half * 256;    // chunk id: 512 chunks of 8 bf16
            const int r  = cc >> 2;             // tile row 0..127
            const int g  = cc & 3;              // k-slot 0..3
            const int sg = g ^ ((r >> 1) & 3);  // swizzled slot (2-way bank = free)

            const float4* pa = reinterpret_cast<const float4*>(
                A + (size_t)(m0 + r) * C_TOT + k0 + g * 8);
            float4 a0 = pa[0], a1 = pa[1];
            bf16x8 wa;
            wa[0]=f2bf(a0.x); wa[1]=f2bf(a0.y); wa[2]=f2bf(a0.z); wa[3]=f2bf(a0.w);
            wa[4]=f2bf(a1.x); wa[5]=f2bf(a1.y); wa[6]=f2bf(a1.z); wa[7]=f2bf(a1.w);
            *reinterpret_cast<bf16x8*>(&As[r * BK + sg * 8]) = wa;

            const float4* pb = reinterpret_cast<const float4*>(
                Bm + (size_t)(n0 + r) * C_TOT + k0 + g * 8);
            float4 b0 = pb[0], b1 = pb[1];
            bf16x8 wb;
            wb[0]=f2bf(b0.x); wb[1]=f2bf(b0.y); wb[2]=f2bf(b0.z); wb[3]=f2bf(b0.w);
            wb[4]=f2bf(b1.x); wb[5]=f2bf(b1.y); wb[6]=f2bf(b1.z); wb[7]=f2bf(b1.w);
            *reinterpret_cast<bf16x8*>(&Bs[r * BK + sg * 8]) = wb;
        }
        __syncthreads();

        // ---- LDS -> fragments -> MFMA ----
        bf16x8 af[4], bfr[4];
        #pragma unroll
        for (int mi = 0; mi < 4; ++mi) {
            const int r  = wr * 64 + mi * 16 + rl;
            const int sg = g_rd ^ ((r >> 1) & 3);
            af[mi] = *reinterpret_cast<const bf16x8*>(&As[r * BK + sg * 8]);
        }
        #pragma unroll
        for (int ni = 0; ni < 4; ++ni) {
            const int r  = wc * 64 + ni * 16 + rl;
            const int sg = g_rd ^ ((r >> 1) & 3);
            bfr[ni] = *reinterpret_cast<const bf16x8*>(&Bs[r * BK + sg * 8]);
        }
        #pragma unroll
        for (int mi = 0; mi < 4; ++mi)
            #pragma unroll
            for (int ni = 0; ni < 4; ++ni)
                acc[mi][ni] = __builtin_amdgcn_mfma_f32_16x16x32_bf16(
                    af[mi], bfr[ni], acc[mi][ni], 0, 0, 0);
        __syncthreads();   // protect LDS before next stage overwrites
    }

    // ---- epilogue: scale by 1/C, store corr, accumulate row sum-of-squares ----
    const float inv_c = 1.0f / (float)C_TOT;
    #pragma unroll
    for (int mi = 0; mi < 4; ++mi) {
        #pragma unroll
        for (int i = 0; i < 4; ++i) {
            const int m = m0 + wr * 64 + mi * 16 + (lane >> 4) * 4 + i;
            float s = 0.0f;
            #pragma unroll
            for (int ni = 0; ni < 4; ++ni) {
                const float v = acc[mi][ni][i] * inv_c;
                out[(size_t)m * M_TOT + n0 + wc * 64 + ni * 16 + rl] = v;
                s += v * v;
            }
            // reduce across the 16 lanes holding this row (xor within lane&15)
            s += __shfl_xor(s, 1);
            s += __shfl_xor(s, 2);
            s += __shfl_xor(s, 4);
            s += __shfl_xor(s, 8);
            if (rl == 0) atomicAdd(&penalty[m], s);
        }
    }
}

// out[m,n] *= rsqrt(penalty[n])   (note: column index, per TF trailing broadcast)
__global__ __launch_bounds__(256) void scale_k(float* __restrict__ out,
                                               const float* __restrict__ penalty)
{
    const unsigned cols4 = M_TOT / 4;            // 1600 float4 per row
    const unsigned total = (unsigned)M_TOT * cols4;   // 10,240,000
    float4* o4 = reinterpret_cast<float4*>(out);
    const float4* p4 = reinterpret_cast<const float4*>(penalty);
    for (unsigned idx = blockIdx.x * blockDim.x + threadIdx.x; idx < total;
         idx += gridDim.x * blockDim.x) {
        const unsigned n4 = idx % cols4;
        const float4 p = p4[n4];
        float4 v = o4[idx];
        v.x *= rsqrtf(p.x);
        v.y *= rsqrtf(p.y);
        v.z *= rsqrtf(p.z);
        v.w *= rsqrtf(p.w);
        o4[idx] = v;
    }
}

extern "C" void kernel_launch(void* const* d_in, const int* in_sizes, int n_in,
                              void* d_out, int out_size, void* d_ws, size_t ws_size,
                              hipStream_t stream) {
    const float* A = (const float*)d_in[0];
    const float* B = (const float*)d_in[1];
    float* out     = (float*)d_out;
    float* penalty = (float*)d_ws;   // 6400 floats = 25.6 KB

    hipMemsetAsync(penalty, 0, M_TOT * sizeof(float), stream);

    dim3 grid(M_TOT / BN, M_TOT / BM);   // 50 x 50
    corr_gemm<<<grid, dim3(256), 0, stream>>>(A, B, out, penalty);

    scale_k<<<2048, 256, 0, stream>>>(out, penalty);
}

// Round 2
// 123.366 us; speedup vs baseline: 1.1221x; 1.1221x over previous
//
#include <hip/hip_runtime.h>

typedef __attribute__((ext_vector_type(8))) short bf16x8;
typedef __attribute__((ext_vector_type(4))) float f32x4;

#define M_TOT 6400   // 80*80 flattened spatial positions
#define C_TOT 256    // channels (K of the GEMM)
#define BM 128
#define BN 128
#define BK 32

// f32 -> bf16 round-to-nearest-even
__device__ __forceinline__ short f2bf(float f) {
    unsigned u = __float_as_uint(f);
    u = (u + 0x7fffu + ((u >> 16) & 1u)) >> 16;
    return (short)u;
}

// async global->LDS, 16B per lane; LDS dst must be wave-uniform base
__device__ __forceinline__ void gload16(const short* g, short* l) {
    __builtin_amdgcn_global_load_lds(
        (const __attribute__((address_space(1))) void*)g,
        (__attribute__((address_space(3))) void*)l, 16, 0, 0);
}

// ---------------- fast path ----------------

__global__ __launch_bounds__(256) void convert_bf16(const float* __restrict__ A,
                                                    const float* __restrict__ Bm,
                                                    short* __restrict__ Ab,
                                                    short* __restrict__ Bb)
{
    const int n8 = M_TOT * C_TOT / 8;   // 204800 chunks of 8 floats per matrix
    for (int i = blockIdx.x * blockDim.x + threadIdx.x; i < 2 * n8;
         i += gridDim.x * blockDim.x) {
        const float* s = (i < n8) ? (A + (size_t)i * 8) : (Bm + (size_t)(i - n8) * 8);
        short* d       = (i < n8) ? (Ab + (size_t)i * 8) : (Bb + (size_t)(i - n8) * 8);
        const float4 v0 = reinterpret_cast<const float4*>(s)[0];
        const float4 v1 = reinterpret_cast<const float4*>(s)[1];
        bf16x8 w;
        w[0]=f2bf(v0.x); w[1]=f2bf(v0.y); w[2]=f2bf(v0.z); w[3]=f2bf(v0.w);
        w[4]=f2bf(v1.x); w[5]=f2bf(v1.y); w[6]=f2bf(v1.z); w[7]=f2bf(v1.w);
        *reinterpret_cast<bf16x8*>(d) = w;
    }
}

// shared main loop: 128x128 tile of dot = Ab * Bb^T (no /C), m97 structure
__device__ __forceinline__ void gemm_tile(const short* __restrict__ Ab,
                                          const short* __restrict__ Bb,
                                          int m0, int n0, int tid,
                                          short* As, short* Bs,
                                          f32x4 acc[4][4])
{
    const int lane = tid & 63;
    const int wave = tid >> 6;
    const int rl   = lane & 15;
    const int g_rd = lane >> 4;
    const int wr   = wave >> 1;
    const int wc   = wave & 1;

    for (int k0 = 0; k0 < C_TOT; k0 += BK) {
        // stage A,B 128x32 bf16 tiles direct to LDS (linear [row][32] layout)
        #pragma unroll
        for (int t = 0; t < 2; ++t) {
            const int c = (wave * 2 + t) * 64 + lane;   // 16B chunk id
            const int r = c >> 2;                       // tile row
            const int g = c & 3;                        // k-slot (8 bf16)
            gload16(Ab + (size_t)(m0 + r) * C_TOT + k0 + g * 8,
                    As + (wave * 2 + t) * 512);
            gload16(Bb + (size_t)(n0 + r) * C_TOT + k0 + g * 8,
                    Bs + (wave * 2 + t) * 512);
        }
        __syncthreads();   // compiler drains vmcnt before barrier

        bf16x8 af[4], bfr[4];
        #pragma unroll
        for (int mi = 0; mi < 4; ++mi)
            af[mi] = *reinterpret_cast<const bf16x8*>(
                &As[(wr * 64 + mi * 16 + rl) * BK + g_rd * 8]);
        #pragma unroll
        for (int ni = 0; ni < 4; ++ni)
            bfr[ni] = *reinterpret_cast<const bf16x8*>(
                &Bs[(wc * 64 + ni * 16 + rl) * BK + g_rd * 8]);
        #pragma unroll
        for (int mi = 0; mi < 4; ++mi)
            #pragma unroll
            for (int ni = 0; ni < 4; ++ni)
                acc[mi][ni] = __builtin_amdgcn_mfma_f32_16x16x32_bf16(
                    af[mi], bfr[ni], acc[mi][ni], 0, 0, 0);
        __syncthreads();
    }
}

// pass 1: P[m] += sum_n dot[m,n]^2
__global__ __launch_bounds__(256) void gemm_penalty(const short* __restrict__ Ab,
                                                    const short* __restrict__ Bb,
                                                    float* __restrict__ P)
{
    __shared__ __align__(16) short As[BM * BK];
    __shared__ __align__(16) short Bs[BN * BK];
    const int tid = threadIdx.x;
    const int m0 = blockIdx.y * BM, n0 = blockIdx.x * BN;
    f32x4 acc[4][4] = {};
    gemm_tile(Ab, Bb, m0, n0, tid, As, Bs, acc);

    const int lane = tid & 63, rl = lane & 15;
    const int wave = tid >> 6, wr = wave >> 1;
    #pragma unroll
    for (int mi = 0; mi < 4; ++mi) {
        #pragma unroll
        for (int i = 0; i < 4; ++i) {
            const int m = m0 + wr * 64 + mi * 16 + (lane >> 4) * 4 + i;
            float s = 0.0f;
            #pragma unroll
            for (int ni = 0; ni < 4; ++ni) {
                const float v = acc[mi][ni][i];
                s += v * v;
            }
            s += __shfl_xor(s, 1);
            s += __shfl_xor(s, 2);
            s += __shfl_xor(s, 4);
            s += __shfl_xor(s, 8);
            if (rl == 0) atomicAdd(&P[m], s);
        }
    }
}

// pass 2: out[m,n] = dot[m,n] * rsqrt(P[n])   (column-indexed, TF broadcast)
__global__ __launch_bounds__(256) void gemm_out(const short* __restrict__ Ab,
                                                const short* __restrict__ Bb,
                                                const float* __restrict__ P,
                                                float* __restrict__ out)
{
    __shared__ __align__(16) short As[BM * BK];
    __shared__ __align__(16) short Bs[BN * BK];
    const int tid = threadIdx.x;
    const int m0 = blockIdx.y * BM, n0 = blockIdx.x * BN;
    f32x4 acc[4][4] = {};
    gemm_tile(Ab, Bb, m0, n0, tid, As, Bs, acc);

    const int lane = tid & 63, rl = lane & 15;
    const int wave = tid >> 6, wr = wave >> 1, wc = wave & 1;
    float rs[4];
    #pragma unroll
    for (int ni = 0; ni < 4; ++ni)
        rs[ni] = rsqrtf(P[n0 + wc * 64 + ni * 16 + rl]);
    #pragma unroll
    for (int mi = 0; mi < 4; ++mi)
        #pragma unroll
        for (int i = 0; i < 4; ++i) {
            const int m = m0 + wr * 64 + mi * 16 + (lane >> 4) * 4 + i;
            #pragma unroll
            for (int ni = 0; ni < 4; ++ni)
                out[(size_t)m * M_TOT + n0 + wc * 64 + ni * 16 + rl] =
                    acc[mi][ni][i] * rs[ni];
        }
}

// ---------------- fallback path (round-1, passing) ----------------

__global__ __launch_bounds__(256) void corr_gemm(const float* __restrict__ A,
                                                 const float* __restrict__ Bm,
                                                 float* __restrict__ out,
                                                 float* __restrict__ penalty)
{
    __shared__ short As[BM * BK];
    __shared__ short Bs[BN * BK];

    const int tid  = threadIdx.x;
    const int lane = tid & 63;
    const int wave = tid >> 6;
    const int wr   = wave >> 1;
    const int wc   = wave & 1;
    const int m0   = blockIdx.y * BM;
    const int n0   = blockIdx.x * BN;
    const int g_rd = lane >> 4;
    const int rl   = lane & 15;

    f32x4 acc[4][4] = {};

    for (int k0 = 0; k0 < C_TOT; k0 += BK) {
        #pragma unroll
        for (int half = 0; half < 2; ++half) {
            const int cc = tid + half * 256;
            const int r  = cc >> 2;
            const int g  = cc & 3;
            const int sg = g ^ ((r >> 1) & 3);

            const float4* pa = reinterpret_cast<const float4*>(
                A + (size_t)(m0 + r) * C_TOT + k0 + g * 8);
            float4 a0 = pa[0], a1 = pa[1];
            bf16x8 wa;
            wa[0]=f2bf(a0.x); wa[1]=f2bf(a0.y); wa[2]=f2bf(a0.z); wa[3]=f2bf(a0.w);
            wa[4]=f2bf(a1.x); wa[5]=f2bf(a1.y); wa[6]=f2bf(a1.z); wa[7]=f2bf(a1.w);
            *reinterpret_cast<bf16x8*>(&As[r * BK + sg * 8]) = wa;

            const float4* pb = reinterpret_cast<const float4*>(
                Bm + (size_t)(n0 + r) * C_TOT + k0 + g * 8);
            float4 b0 = pb[0], b1 = pb[1];
            bf16x8 wb;
            wb[0]=f2bf(b0.x); wb[1]=f2bf(b0.y); wb[2]=f2bf(b0.z); wb[3]=f2bf(b0.w);
            wb[4]=f2bf(b1.x); wb[5]=f2bf(b1.y); wb[6]=f2bf(b1.z); wb[7]=f2bf(b1.w);
            *reinterpret_cast<bf16x8*>(&Bs[r * BK + sg * 8]) = wb;
        }
        __syncthreads();

        bf16x8 af[4], bfr[4];
        #pragma unroll
        for (int mi = 0; mi < 4; ++mi) {
            const int r  = wr * 64 + mi * 16 + rl;
            const int sg = g_rd ^ ((r >> 1) & 3);
            af[mi] = *reinterpret_cast<const bf16x8*>(&As[r * BK + sg * 8]);
        }
        #pragma unroll
        for (int ni = 0; ni < 4; ++ni) {
            const int r  = wc * 64 + ni * 16 + rl;
            const int sg = g_rd ^ ((r >> 1) & 3);
            bfr[ni] = *reinterpret_cast<const bf16x8*>(&Bs[r * BK + sg * 8]);
        }
        #pragma unroll
        for (int mi = 0; mi < 4; ++mi)
            #pragma unroll
            for (int ni = 0; ni < 4; ++ni)
                acc[mi][ni] = __builtin_amdgcn_mfma_f32_16x16x32_bf16(
                    af[mi], bfr[ni], acc[mi][ni], 0, 0, 0);
        __syncthreads();
    }

    const float inv_c = 1.0f / (float)C_TOT;
    #pragma unroll
    for (int mi = 0; mi < 4; ++mi) {
        #pragma unroll
        for (int i = 0; i < 4; ++i) {
            const int m = m0 + wr * 64 + mi * 16 + (lane >> 4) * 4 + i;
            float s = 0.0f;
            #pragma unroll
            for (int ni = 0; ni < 4; ++ni) {
                const float v = acc[mi][ni][i] * inv_c;
                out[(size_t)m * M_TOT + n0 + wc * 64 + ni * 16 + rl] = v;
                s += v * v;
            }
            s += __shfl_xor(s, 1);
            s += __shfl_xor(s, 2);
            s += __shfl_xor(s, 4);
            s += __shfl_xor(s, 8);
            if (rl == 0) atomicAdd(&penalty[m], s);
        }
    }
}

__global__ __launch_bounds__(256) void scale_k(float* __restrict__ out,
                                               const float* __restrict__ penalty)
{
    const unsigned cols4 = M_TOT / 4;
    const unsigned total = (unsigned)M_TOT * cols4;
    float4* o4 = reinterpret_cast<float4*>(out);
    const float4* p4 = reinterpret_cast<const float4*>(penalty);
    for (unsigned idx = blockIdx.x * blockDim.x + threadIdx.x; idx < total;
         idx += gridDim.x * blockDim.x) {
        const unsigned n4 = idx % cols4;
        const float4 p = p4[n4];
        float4 v = o4[idx];
        v.x *= rsqrtf(p.x);
        v.y *= rsqrtf(p.y);
        v.z *= rsqrtf(p.z);
        v.w *= rsqrtf(p.w);
        o4[idx] = v;
    }
}

// ---------------- launch ----------------

extern "C" void kernel_launch(void* const* d_in, const int* in_sizes, int n_in,
                              void* d_out, int out_size, void* d_ws, size_t ws_size,
                              hipStream_t stream) {
    const float* A = (const float*)d_in[0];
    const float* B = (const float*)d_in[1];
    float* out     = (float*)d_out;

    const size_t mat_shorts = (size_t)M_TOT * C_TOT;           // 1,638,400
    const size_t need = 2 * mat_shorts * sizeof(short) + M_TOT * sizeof(float);

    if (ws_size >= need) {
        short* Ab = (short*)d_ws;
        short* Bb = Ab + mat_shorts;
        float* P  = (float*)(Bb + mat_shorts);

        hipMemsetAsync(P, 0, M_TOT * sizeof(float), stream);
        convert_bf16<<<1600, 256, 0, stream>>>(A, B, Ab, Bb);

        dim3 grid(M_TOT / BN, M_TOT / BM);   // 50 x 50
        gemm_penalty<<<grid, dim3(256), 0, stream>>>(Ab, Bb, P);
        gemm_out<<<grid, dim3(256), 0, stream>>>(Ab, Bb, P, out);
    } else {
        float* penalty = (float*)d_ws;   // 25.6 KB
        hipMemsetAsync(penalty, 0, M_TOT * sizeof(float), stream);
        dim3 grid(M_TOT / BN, M_TOT / BM);
        corr_gemm<<<grid, dim3(256), 0, stream>>>(A, B, out, penalty);
        scale_k<<<2048, 256, 0, stream>>>(out, penalty);
    }
}

// Round 3
// 119.207 us; speedup vs baseline: 1.1612x; 1.0349x over previous
//
#include <hip/hip_runtime.h>

typedef __attribute__((ext_vector_type(8))) short bf16x8;
typedef __attribute__((ext_vector_type(4))) float f32x4;

#define M_TOT 6400   // 80*80 flattened spatial positions
#define C_TOT 256    // channels (K of the GEMM)
#define BM 128
#define BN 128
#define BK 32

#define VMCNT0 asm volatile("s_waitcnt vmcnt(0)" ::: "memory")
#define SBAR   __builtin_amdgcn_s_barrier()

// f32 -> bf16 round-to-nearest-even
__device__ __forceinline__ short f2bf(float f) {
    unsigned u = __float_as_uint(f);
    u = (u + 0x7fffu + ((u >> 16) & 1u)) >> 16;
    return (short)u;
}

// async global->LDS, 16B per lane; LDS dst is wave-uniform base + lane*16
__device__ __forceinline__ void gload16(const short* g, short* l) {
    __builtin_amdgcn_global_load_lds(
        (const __attribute__((address_space(1))) void*)g,
        (__attribute__((address_space(3))) void*)l, 16, 0, 0);
}

// ---------------- fast path ----------------

__global__ __launch_bounds__(256) void convert_bf16(const float* __restrict__ A,
                                                    const float* __restrict__ Bm,
                                                    short* __restrict__ Ab,
                                                    short* __restrict__ Bb,
                                                    float* __restrict__ P)
{
    if (blockIdx.x == 0) {
        for (int j = threadIdx.x; j < M_TOT; j += 256) P[j] = 0.0f;
    }
    const int n8 = M_TOT * C_TOT / 8;   // 204800 chunks of 8 floats per matrix
    for (int i = blockIdx.x * blockDim.x + threadIdx.x; i < 2 * n8;
         i += gridDim.x * blockDim.x) {
        const float* s = (i < n8) ? (A + (size_t)i * 8) : (Bm + (size_t)(i - n8) * 8);
        short* d       = (i < n8) ? (Ab + (size_t)i * 8) : (Bb + (size_t)(i - n8) * 8);
        const float4 v0 = reinterpret_cast<const float4*>(s)[0];
        const float4 v1 = reinterpret_cast<const float4*>(s)[1];
        bf16x8 w;
        w[0]=f2bf(v0.x); w[1]=f2bf(v0.y); w[2]=f2bf(v0.z); w[3]=f2bf(v0.w);
        w[4]=f2bf(v1.x); w[5]=f2bf(v1.y); w[6]=f2bf(v1.z); w[7]=f2bf(v1.w);
        *reinterpret_cast<bf16x8*>(d) = w;
    }
}

// stage one 128x32 bf16 K-tile of A and B into LDS (linear layout, r*32+g*8)
__device__ __forceinline__ void stage_tiles(const short* __restrict__ Ab,
                                            const short* __restrict__ Bb,
                                            int m0, int n0, int k0,
                                            short* As, short* Bs,
                                            int wave, int lane)
{
    #pragma unroll
    for (int t = 0; t < 2; ++t) {
        const int c = (wave * 2 + t) * 64 + lane;   // 16B-chunk id 0..511
        const int r = c >> 2;                        // tile row
        const int g = c & 3;                         // k-slot (8 bf16)
        gload16(Ab + (size_t)(m0 + r) * C_TOT + k0 + g * 8, As + (wave * 2 + t) * 512);
        gload16(Bb + (size_t)(n0 + r) * C_TOT + k0 + g * 8, Bs + (wave * 2 + t) * 512);
    }
}

// 2-phase pipelined 128x128 tile of dot = Ab * Bb^T (no /C)
// Sm = [buf][A/B][4096 shorts]; one barrier + one vmcnt drain per K-step,
// placed AFTER the MFMAs so next-tile loads overlap current compute.
__device__ __forceinline__ void gemm_tile(const short* __restrict__ Ab,
                                          const short* __restrict__ Bb,
                                          int m0, int n0, int tid,
                                          short (*Sm)[2][4096],
                                          f32x4 acc[4][4])
{
    const int lane = tid & 63;
    const int wave = tid >> 6;
    const int rl   = lane & 15;
    const int g_rd = lane >> 4;
    const int wr   = wave >> 1;
    const int wc   = wave & 1;

    stage_tiles(Ab, Bb, m0, n0, 0, &Sm[0][0][0], &Sm[0][1][0], wave, lane);
    VMCNT0; SBAR;

    #pragma unroll
    for (int kt = 0; kt < 8; ++kt) {
        const int cur = kt & 1;
        if (kt < 7)
            stage_tiles(Ab, Bb, m0, n0, (kt + 1) * BK,
                        &Sm[cur ^ 1][0][0], &Sm[cur ^ 1][1][0], wave, lane);

        bf16x8 af[4], bfr[4];
        #pragma unroll
        for (int mi = 0; mi < 4; ++mi)
            af[mi] = *reinterpret_cast<const bf16x8*>(
                &Sm[cur][0][(wr * 64 + mi * 16 + rl) * BK + g_rd * 8]);
        #pragma unroll
        for (int ni = 0; ni < 4; ++ni)
            bfr[ni] = *reinterpret_cast<const bf16x8*>(
                &Sm[cur][1][(wc * 64 + ni * 16 + rl) * BK + g_rd * 8]);
        #pragma unroll
        for (int mi = 0; mi < 4; ++mi)
            #pragma unroll
            for (int ni = 0; ni < 4; ++ni)
                acc[mi][ni] = __builtin_amdgcn_mfma_f32_16x16x32_bf16(
                    af[mi], bfr[ni], acc[mi][ni], 0, 0, 0);

        if (kt < 7) { VMCNT0; SBAR; }
    }
}

// pass 1: P[m] += sum_n dot[m,n]^2
__global__ __launch_bounds__(256) void gemm_penalty(const short* __restrict__ Ab,
                                                    const short* __restrict__ Bb,
                                                    float* __restrict__ P)
{
    __shared__ __align__(16) short Sm[2][2][4096];
    const int tid = threadIdx.x;
    const int m0 = blockIdx.y * BM, n0 = blockIdx.x * BN;
    f32x4 acc[4][4] = {};
    gemm_tile(Ab, Bb, m0, n0, tid, Sm, acc);

    const int lane = tid & 63, rl = lane & 15;
    const int wave = tid >> 6, wr = wave >> 1;
    #pragma unroll
    for (int mi = 0; mi < 4; ++mi) {
        #pragma unroll
        for (int i = 0; i < 4; ++i) {
            const int m = m0 + wr * 64 + mi * 16 + (lane >> 4) * 4 + i;
            float s = 0.0f;
            #pragma unroll
            for (int ni = 0; ni < 4; ++ni) {
                const float v = acc[mi][ni][i];
                s += v * v;
            }
            s += __shfl_xor(s, 1);
            s += __shfl_xor(s, 2);
            s += __shfl_xor(s, 4);
            s += __shfl_xor(s, 8);
            if (rl == 0) atomicAdd(&P[m], s);
        }
    }
}

// pass 2: out[m,n] = dot[m,n] * rsqrt(P[n])   (column-indexed, TF broadcast)
// epilogue transposes through wave-private LDS so stores are float4/full-line.
__global__ __launch_bounds__(256) void gemm_out(const short* __restrict__ Ab,
                                                const short* __restrict__ Bb,
                                                const float* __restrict__ P,
                                                float* __restrict__ out)
{
    __shared__ __align__(16) short Sm[2][2][4096];   // 32 KB, reused by epilogue
    const int tid = threadIdx.x;
    const int lane = tid & 63, rl = lane & 15;
    const int wave = tid >> 6, wr = wave >> 1, wc = wave & 1;
    const int m0 = blockIdx.y * BM, n0 = blockIdx.x * BN;

    float rs[4];
    #pragma unroll
    for (int ni = 0; ni < 4; ++ni)
        rs[ni] = rsqrtf(P[n0 + wc * 64 + ni * 16 + rl]);

    f32x4 acc[4][4] = {};
    gemm_tile(Ab, Bb, m0, n0, tid, Sm, acc);

    SBAR;   // all waves done with K-loop LDS before epilogue reuse

    // wave-private 16x68 f32 scratch (padded: writes 2-way banks, reads 2-way)
    float* Es = reinterpret_cast<float*>(Sm) + wave * 1088;
    #pragma unroll
    for (int mi = 0; mi < 4; ++mi) {
        #pragma unroll
        for (int ni = 0; ni < 4; ++ni)
            #pragma unroll
            for (int i = 0; i < 4; ++i)
                Es[((lane >> 4) * 4 + i) * 68 + ni * 16 + rl] = acc[mi][ni][i] * rs[ni];
        // read back row-major as float4, store coalesced (256B per 16 lanes)
        #pragma unroll
        for (int it = 0; it < 4; ++it) {
            const int f   = it * 64 + lane;
            const int row = f >> 4;          // 0..15
            const int c4  = f & 15;          // float4 column
            const float4 v = *reinterpret_cast<const float4*>(&Es[row * 68 + c4 * 4]);
            const int m = m0 + wr * 64 + mi * 16 + row;
            *reinterpret_cast<float4*>(&out[(size_t)m * M_TOT + n0 + wc * 64 + c4 * 4]) = v;
        }
    }
}

// ---------------- fallback path (round-1, passing) ----------------

__global__ __launch_bounds__(256) void corr_gemm(const float* __restrict__ A,
                                                 const float* __restrict__ Bm,
                                                 float* __restrict__ out,
                                                 float* __restrict__ penalty)
{
    __shared__ short As[BM * BK];
    __shared__ short Bs[BN * BK];

    const int tid  = threadIdx.x;
    const int lane = tid & 63;
    const int wave = tid >> 6;
    const int wr   = wave >> 1;
    const int wc   = wave & 1;
    const int m0   = blockIdx.y * BM;
    const int n0   = blockIdx.x * BN;
    const int g_rd = lane >> 4;
    const int rl   = lane & 15;

    f32x4 acc[4][4] = {};

    for (int k0 = 0; k0 < C_TOT; k0 += BK) {
        #pragma unroll
        for (int half = 0; half < 2; ++half) {
            const int cc = tid + half * 256;
            const int r  = cc >> 2;
            const int g  = cc & 3;
            const int sg = g ^ ((r >> 1) & 3);

            const float4* pa = reinterpret_cast<const float4*>(
                A + (size_t)(m0 + r) * C_TOT + k0 + g * 8);
            float4 a0 = pa[0], a1 = pa[1];
            bf16x8 wa;
            wa[0]=f2bf(a0.x); wa[1]=f2bf(a0.y); wa[2]=f2bf(a0.z); wa[3]=f2bf(a0.w);
            wa[4]=f2bf(a1.x); wa[5]=f2bf(a1.y); wa[6]=f2bf(a1.z); wa[7]=f2bf(a1.w);
            *reinterpret_cast<bf16x8*>(&As[r * BK + sg * 8]) = wa;

            const float4* pb = reinterpret_cast<const float4*>(
                Bm + (size_t)(n0 + r) * C_TOT + k0 + g * 8);
            float4 b0 = pb[0], b1 = pb[1];
            bf16x8 wb;
            wb[0]=f2bf(b0.x); wb[1]=f2bf(b0.y); wb[2]=f2bf(b0.z); wb[3]=f2bf(b0.w);
            wb[4]=f2bf(b1.x); wb[5]=f2bf(b1.y); wb[6]=f2bf(b1.z); wb[7]=f2bf(b1.w);
            *reinterpret_cast<bf16x8*>(&Bs[r * BK + sg * 8]) = wb;
        }
        __syncthreads();

        bf16x8 af[4], bfr[4];
        #pragma unroll
        for (int mi = 0; mi < 4; ++mi) {
            const int r  = wr * 64 + mi * 16 + rl;
            const int sg = g_rd ^ ((r >> 1) & 3);
            af[mi] = *reinterpret_cast<const bf16x8*>(&As[r * BK + sg * 8]);
        }
        #pragma unroll
        for (int ni = 0; ni < 4; ++ni) {
            const int r  = wc * 64 + ni * 16 + rl;
            const int sg = g_rd ^ ((r >> 1) & 3);
            bfr[ni] = *reinterpret_cast<const bf16x8*>(&Bs[r * BK + sg * 8]);
        }
        #pragma unroll
        for (int mi = 0; mi < 4; ++mi)
            #pragma unroll
            for (int ni = 0; ni < 4; ++ni)
                acc[mi][ni] = __builtin_amdgcn_mfma_f32_16x16x32_bf16(
                    af[mi], bfr[ni], acc[mi][ni], 0, 0, 0);
        __syncthreads();
    }

    const float inv_c = 1.0f / (float)C_TOT;
    #pragma unroll
    for (int mi = 0; mi < 4; ++mi) {
        #pragma unroll
        for (int i = 0; i < 4; ++i) {
            const int m = m0 + wr * 64 + mi * 16 + (lane >> 4) * 4 + i;
            float s = 0.0f;
            #pragma unroll
            for (int ni = 0; ni < 4; ++ni) {
                const float v = acc[mi][ni][i] * inv_c;
                out[(size_t)m * M_TOT + n0 + wc * 64 + ni * 16 + rl] = v;
                s += v * v;
            }
            s += __shfl_xor(s, 1);
            s += __shfl_xor(s, 2);
            s += __shfl_xor(s, 4);
            s += __shfl_xor(s, 8);
            if (rl == 0) atomicAdd(&penalty[m], s);
        }
    }
}

__global__ __launch_bounds__(256) void scale_k(float* __restrict__ out,
                                               const float* __restrict__ penalty)
{
    const unsigned cols4 = M_TOT / 4;
    const unsigned total = (unsigned)M_TOT * cols4;
    float4* o4 = reinterpret_cast<float4*>(out);
    const float4* p4 = reinterpret_cast<const float4*>(penalty);
    for (unsigned idx = blockIdx.x * blockDim.x + threadIdx.x; idx < total;
         idx += gridDim.x * blockDim.x) {
        const unsigned n4 = idx % cols4;
        const float4 p = p4[n4];
        float4 v = o4[idx];
        v.x *= rsqrtf(p.x);
        v.y *= rsqrtf(p.y);
        v.z *= rsqrtf(p.z);
        v.w *= rsqrtf(p.w);
        o4[idx] = v;
    }
}

// ---------------- launch ----------------

extern "C" void kernel_launch(void* const* d_in, const int* in_sizes, int n_in,
                              void* d_out, int out_size, void* d_ws, size_t ws_size,
                              hipStream_t stream) {
    const float* A = (const float*)d_in[0];
    const float* B = (const float*)d_in[1];
    float* out     = (float*)d_out;

    const size_t mat_shorts = (size_t)M_TOT * C_TOT;           // 1,638,400
    const size_t need = 2 * mat_shorts * sizeof(short) + M_TOT * sizeof(float);

    if (ws_size >= need) {
        short* Ab = (short*)d_ws;
        short* Bb = Ab + mat_shorts;
        float* P  = (float*)(Bb + mat_shorts);

        convert_bf16<<<1600, 256, 0, stream>>>(A, B, Ab, Bb, P);

        dim3 grid(M_TOT / BN, M_TOT / BM);   // 50 x 50
        gemm_penalty<<<grid, dim3(256), 0, stream>>>(Ab, Bb, P);
        gemm_out<<<grid, dim3(256), 0, stream>>>(Ab, Bb, P, out);
    } else {
        float* penalty = (float*)d_ws;   // 25.6 KB
        hipMemsetAsync(penalty, 0, M_TOT * sizeof(float), stream);
        dim3 grid(M_TOT / BN, M_TOT / BM);
        corr_gemm<<<grid, dim3(256), 0, stream>>>(A, B, out, penalty);
        scale_k<<<2048, 256, 0, stream>>>(out, penalty);
    }
}

// Round 4
// 90.688 us; speedup vs baseline: 1.5264x; 1.3145x over previous
//
#include <hip/hip_runtime.h>

typedef __attribute__((ext_vector_type(8))) short bf16x8;
typedef __attribute__((ext_vector_type(4))) float f32x4;

#define M_TOT 6400   // 80*80 flattened spatial positions
#define C_TOT 256    // channels (K of the main GEMM)
#define BM 128
#define BN 128
#define BK 32
#define GK_CHUNKS 20           // K-split for Gram kernel: 6400 = 20 * 320
#define GK_STEPS  10           // 320 / 32

#define VMCNT0 asm volatile("s_waitcnt vmcnt(0)" ::: "memory")
#define SBAR   __builtin_amdgcn_s_barrier()

// f32 -> bf16 round-to-nearest-even
__device__ __forceinline__ short f2bf(float f) {
    unsigned u = __float_as_uint(f);
    u = (u + 0x7fffu + ((u >> 16) & 1u)) >> 16;
    return (short)u;
}
__device__ __forceinline__ float bf2f(short s) {
    return __uint_as_float(((unsigned)(unsigned short)s) << 16);
}

// async global->LDS, 16B per lane; LDS dst is wave-uniform base + lane*16
__device__ __forceinline__ void gload16(const short* g, short* l) {
    __builtin_amdgcn_global_load_lds(
        (const __attribute__((address_space(1))) void*)g,
        (__attribute__((address_space(3))) void*)l, 16, 0, 0);
}

// ---------------- conversion / transpose ----------------

__global__ __launch_bounds__(256) void convert_bf16(const float* __restrict__ A,
                                                    const float* __restrict__ Bm,
                                                    short* __restrict__ Ab,
                                                    short* __restrict__ Bb)
{
    const int n8 = M_TOT * C_TOT / 8;   // 204800 chunks of 8 floats per matrix
    for (int i = blockIdx.x * blockDim.x + threadIdx.x; i < 2 * n8;
         i += gridDim.x * blockDim.x) {
        const float* s = (i < n8) ? (A + (size_t)i * 8) : (Bm + (size_t)(i - n8) * 8);
        short* d       = (i < n8) ? (Ab + (size_t)i * 8) : (Bb + (size_t)(i - n8) * 8);
        const float4 v0 = reinterpret_cast<const float4*>(s)[0];
        const float4 v1 = reinterpret_cast<const float4*>(s)[1];
        bf16x8 w;
        w[0]=f2bf(v0.x); w[1]=f2bf(v0.y); w[2]=f2bf(v0.z); w[3]=f2bf(v0.w);
        w[4]=f2bf(v1.x); w[5]=f2bf(v1.y); w[6]=f2bf(v1.z); w[7]=f2bf(v1.w);
        *reinterpret_cast<bf16x8*>(d) = w;
    }
}

// Bt[c][n] = bf16(Bm[n][c]);  64x64 tiles through LDS
__global__ __launch_bounds__(256) void transpose_b(const float* __restrict__ Bm,
                                                   short* __restrict__ Bt)
{
    __shared__ __align__(16) short Lb[64][72];   // +8 pad, 16B-aligned rows
    const int t  = threadIdx.x;
    const int n0 = blockIdx.x * 64;
    const int c0 = blockIdx.y * 64;
    const int r  = t >> 2;
    const int cb = (t & 3) * 16;

    const float4* src = reinterpret_cast<const float4*>(
        Bm + (size_t)(n0 + r) * C_TOT + c0 + cb);
    const float4 v0 = src[0], v1 = src[1], v2 = src[2], v3 = src[3];
    bf16x8 w0, w1;
    w0[0]=f2bf(v0.x); w0[1]=f2bf(v0.y); w0[2]=f2bf(v0.z); w0[3]=f2bf(v0.w);
    w0[4]=f2bf(v1.x); w0[5]=f2bf(v1.y); w0[6]=f2bf(v1.z); w0[7]=f2bf(v1.w);
    w1[0]=f2bf(v2.x); w1[1]=f2bf(v2.y); w1[2]=f2bf(v2.z); w1[3]=f2bf(v2.w);
    w1[4]=f2bf(v3.x); w1[5]=f2bf(v3.y); w1[6]=f2bf(v3.z); w1[7]=f2bf(v3.w);
    *reinterpret_cast<bf16x8*>(&Lb[r][cb])     = w0;
    *reinterpret_cast<bf16x8*>(&Lb[r][cb + 8]) = w1;
    __syncthreads();

    #pragma unroll
    for (int p = 0; p < 2; ++p) {
        const int q = t + p * 256;
        const int c = q >> 3;        // 0..63 output row (channel)
        const int h = q & 7;         // 8-col group
        bf16x8 w;
        #pragma unroll
        for (int j = 0; j < 8; ++j) w[j] = Lb[h * 8 + j][c];
        *reinterpret_cast<bf16x8*>(&Bt[(size_t)(c0 + c) * M_TOT + n0 + h * 8]) = w;
    }
}

// ---------------- generalized 2-phase pipelined 128x128 GEMM tile ----------------
// dot[m,n] = sum_k A[m0+m][kb+k] * B[n0+n][kb+k], both row-major, f32 accum.

__device__ __forceinline__ void stage_tiles_g(const short* __restrict__ A,
                                              const short* __restrict__ B,
                                              int m0, int n0, int k0,
                                              int lda, int ldb,
                                              short* As, short* Bs,
                                              int wave, int lane)
{
    #pragma unroll
    for (int t = 0; t < 2; ++t) {
        const int c = (wave * 2 + t) * 64 + lane;   // 16B-chunk id 0..511
        const int r = c >> 2;                        // tile row
        const int g = c & 3;                         // k-slot (8 bf16)
        gload16(A + (size_t)(m0 + r) * lda + k0 + g * 8, As + (wave * 2 + t) * 512);
        gload16(B + (size_t)(n0 + r) * ldb + k0 + g * 8, Bs + (wave * 2 + t) * 512);
    }
}

template<int KSTEPS>
__device__ __forceinline__ void gemm_tile_g(const short* __restrict__ A,
                                            const short* __restrict__ B,
                                            int m0, int n0, int kbase,
                                            int lda, int ldb, int tid,
                                            short (*Sm)[2][4096],
                                            f32x4 acc[4][4])
{
    const int lane = tid & 63;
    const int wave = tid >> 6;
    const int rl   = lane & 15;
    const int g_rd = lane >> 4;
    const int wr   = wave >> 1;
    const int wc   = wave & 1;

    stage_tiles_g(A, B, m0, n0, kbase, lda, ldb, &Sm[0][0][0], &Sm[0][1][0], wave, lane);
    VMCNT0; SBAR;

    #pragma unroll
    for (int kt = 0; kt < KSTEPS; ++kt) {
        const int cur = kt & 1;
        if (kt < KSTEPS - 1)
            stage_tiles_g(A, B, m0, n0, kbase + (kt + 1) * BK, lda, ldb,
                          &Sm[cur ^ 1][0][0], &Sm[cur ^ 1][1][0], wave, lane);

        bf16x8 af[4], bfr[4];
        #pragma unroll
        for (int mi = 0; mi < 4; ++mi)
            af[mi] = *reinterpret_cast<const bf16x8*>(
                &Sm[cur][0][(wr * 64 + mi * 16 + rl) * BK + g_rd * 8]);
        #pragma unroll
        for (int ni = 0; ni < 4; ++ni)
            bfr[ni] = *reinterpret_cast<const bf16x8*>(
                &Sm[cur][1][(wc * 64 + ni * 16 + rl) * BK + g_rd * 8]);
        #pragma unroll
        for (int mi = 0; mi < 4; ++mi)
            #pragma unroll
            for (int ni = 0; ni < 4; ++ni)
                acc[mi][ni] = __builtin_amdgcn_mfma_f32_16x16x32_bf16(
                    af[mi], bfr[ni], acc[mi][ni], 0, 0, 0);

        if (kt < KSTEPS - 1) { VMCNT0; SBAR; }
    }
}

// ---------------- Gram path ----------------

// partial G: Gp[z][c][c'] = sum_{n in chunk z} Bt[c][n] * Bt[c'][n]
__global__ __launch_bounds__(256) void gemm_G(const short* __restrict__ Bt,
                                              float* __restrict__ Gp)
{
    __shared__ __align__(16) short Sm[2][2][4096];
    const int tid = threadIdx.x;
    const int m0 = blockIdx.y * BM, n0 = blockIdx.x * BN;
    const int z  = blockIdx.z;
    f32x4 acc[4][4] = {};
    gemm_tile_g<GK_STEPS>(Bt, Bt, m0, n0, z * (M_TOT / GK_CHUNKS),
                          M_TOT, M_TOT, tid, Sm, acc);

    float* dst = Gp + (size_t)z * (C_TOT * C_TOT);
    const int lane = tid & 63, rl = lane & 15;
    const int wave = tid >> 6, wr = wave >> 1, wc = wave & 1;
    #pragma unroll
    for (int mi = 0; mi < 4; ++mi)
        #pragma unroll
        for (int i = 0; i < 4; ++i) {
            const int m = m0 + wr * 64 + mi * 16 + (lane >> 4) * 4 + i;
            #pragma unroll
            for (int ni = 0; ni < 4; ++ni)
                dst[m * C_TOT + n0 + wc * 64 + ni * 16 + rl] = acc[mi][ni][i];
        }
}

// Gb = bf16( sum_z Gp[z] )
__global__ __launch_bounds__(256) void g_reduce(const float* __restrict__ Gp,
                                                short* __restrict__ Gb)
{
    const int i4 = blockIdx.x * 256 + threadIdx.x;   // 16384 float4 groups
    float4 s = make_float4(0.f, 0.f, 0.f, 0.f);
    for (int z = 0; z < GK_CHUNKS; ++z) {
        const float4 v = reinterpret_cast<const float4*>(
            Gp + (size_t)z * (C_TOT * C_TOT))[i4];
        s.x += v.x; s.y += v.y; s.z += v.z; s.w += v.w;
    }
    short4 o;
    o.x = f2bf(s.x); o.y = f2bf(s.y); o.z = f2bf(s.z); o.w = f2bf(s.w);
    reinterpret_cast<short4*>(Gb)[i4] = o;
}

// P[m] = A[m]^T G A[m] = sum_{c'} (sum_c a[m,c] Gb[c'][c]) * a[m,c']  (G symmetric)
__global__ __launch_bounds__(256) void penalty_G(const short* __restrict__ Ab,
                                                 const short* __restrict__ Gb,
                                                 float* __restrict__ P)
{
    __shared__ __align__(16) short Sm[2][2][4096];
    __shared__ float q_lds[BM];
    const int tid = threadIdx.x;
    const int m0 = blockIdx.x * BM;
    const int lane = tid & 63, rl = lane & 15;
    const int wave = tid >> 6, wr = wave >> 1, wc = wave & 1;

    if (tid < BM) q_lds[tid] = 0.0f;
    __syncthreads();

    #pragma unroll
    for (int nt = 0; nt < 2; ++nt) {
        f32x4 acc[4][4] = {};
        gemm_tile_g<8>(Ab, Gb, m0, nt * BN, 0, C_TOT, C_TOT, tid, Sm, acc);
        const int n0 = nt * BN;
        #pragma unroll
        for (int mi = 0; mi < 4; ++mi)
            #pragma unroll
            for (int i = 0; i < 4; ++i) {
                const int m = m0 + wr * 64 + mi * 16 + (lane >> 4) * 4 + i;
                float s = 0.0f;
                #pragma unroll
                for (int ni = 0; ni < 4; ++ni) {
                    const int cp = n0 + wc * 64 + ni * 16 + rl;
                    s += acc[mi][ni][i] * bf2f(Ab[(size_t)m * C_TOT + cp]);
                }
                s += __shfl_xor(s, 1);
                s += __shfl_xor(s, 2);
                s += __shfl_xor(s, 4);
                s += __shfl_xor(s, 8);
                if (rl == 0) atomicAdd(&q_lds[m - m0], s);
            }
    }
    __syncthreads();
    if (tid < BM) P[m0 + tid] = q_lds[tid];
}

// ---------------- output GEMM (unchanged from round 3) ----------------

__global__ __launch_bounds__(256) void gemm_out(const short* __restrict__ Ab,
                                                const short* __restrict__ Bb,
                                                const float* __restrict__ P,
                                                float* __restrict__ out)
{
    __shared__ __align__(16) short Sm[2][2][4096];   // 32 KB, reused by epilogue
    const int tid = threadIdx.x;
    const int lane = tid & 63, rl = lane & 15;
    const int wave = tid >> 6, wr = wave >> 1, wc = wave & 1;
    const int m0 = blockIdx.y * BM, n0 = blockIdx.x * BN;

    float rs[4];
    #pragma unroll
    for (int ni = 0; ni < 4; ++ni)
        rs[ni] = rsqrtf(P[n0 + wc * 64 + ni * 16 + rl]);

    f32x4 acc[4][4] = {};
    gemm_tile_g<8>(Ab, Bb, m0, n0, 0, C_TOT, C_TOT, tid, Sm, acc);

    SBAR;   // all waves done with K-loop LDS before epilogue reuse

    // wave-private 16x68 f32 scratch (padded)
    float* Es = reinterpret_cast<float*>(Sm) + wave * 1088;
    #pragma unroll
    for (int mi = 0; mi < 4; ++mi) {
        #pragma unroll
        for (int ni = 0; ni < 4; ++ni)
            #pragma unroll
            for (int i = 0; i < 4; ++i)
                Es[((lane >> 4) * 4 + i) * 68 + ni * 16 + rl] = acc[mi][ni][i] * rs[ni];
        #pragma unroll
        for (int it = 0; it < 4; ++it) {
            const int f   = it * 64 + lane;
            const int row = f >> 4;
            const int c4  = f & 15;
            const float4 v = *reinterpret_cast<const float4*>(&Es[row * 68 + c4 * 4]);
            const int m = m0 + wr * 64 + mi * 16 + row;
            *reinterpret_cast<float4*>(&out[(size_t)m * M_TOT + n0 + wc * 64 + c4 * 4]) = v;
        }
    }
}

// ---------------- mid fallback: two-GEMM (round-3) ----------------

__global__ __launch_bounds__(256) void gemm_penalty(const short* __restrict__ Ab,
                                                    const short* __restrict__ Bb,
                                                    float* __restrict__ P)
{
    __shared__ __align__(16) short Sm[2][2][4096];
    const int tid = threadIdx.x;
    const int m0 = blockIdx.y * BM, n0 = blockIdx.x * BN;
    f32x4 acc[4][4] = {};
    gemm_tile_g<8>(Ab, Bb, m0, n0, 0, C_TOT, C_TOT, tid, Sm, acc);

    const int lane = tid & 63, rl = lane & 15;
    const int wave = tid >> 6, wr = wave >> 1;
    #pragma unroll
    for (int mi = 0; mi < 4; ++mi) {
        #pragma unroll
        for (int i = 0; i < 4; ++i) {
            const int m = m0 + wr * 64 + mi * 16 + (lane >> 4) * 4 + i;
            float s = 0.0f;
            #pragma unroll
            for (int ni = 0; ni < 4; ++ni) {
                const float v = acc[mi][ni][i];
                s += v * v;
            }
            s += __shfl_xor(s, 1);
            s += __shfl_xor(s, 2);
            s += __shfl_xor(s, 4);
            s += __shfl_xor(s, 8);
            if (rl == 0) atomicAdd(&P[m], s);
        }
    }
}

// ---------------- final fallback (round-1) ----------------

__global__ __launch_bounds__(256) void corr_gemm(const float* __restrict__ A,
                                                 const float* __restrict__ Bm,
                                                 float* __restrict__ out,
                                                 float* __restrict__ penalty)
{
    __shared__ short As[BM * BK];
    __shared__ short Bs[BN * BK];

    const int tid  = threadIdx.x;
    const int lane = tid & 63;
    const int wave = tid >> 6;
    const int wr   = wave >> 1;
    const int wc   = wave & 1;
    const int m0   = blockIdx.y * BM;
    const int n0   = blockIdx.x * BN;
    const int g_rd = lane >> 4;
    const int rl   = lane & 15;

    f32x4 acc[4][4] = {};

    for (int k0 = 0; k0 < C_TOT; k0 += BK) {
        #pragma unroll
        for (int half = 0; half < 2; ++half) {
            const int cc = tid + half * 256;
            const int r  = cc >> 2;
            const int g  = cc & 3;
            const int sg = g ^ ((r >> 1) & 3);

            const float4* pa = reinterpret_cast<const float4*>(
                A + (size_t)(m0 + r) * C_TOT + k0 + g * 8);
            float4 a0 = pa[0], a1 = pa[1];
            bf16x8 wa;
            wa[0]=f2bf(a0.x); wa[1]=f2bf(a0.y); wa[2]=f2bf(a0.z); wa[3]=f2bf(a0.w);
            wa[4]=f2bf(a1.x); wa[5]=f2bf(a1.y); wa[6]=f2bf(a1.z); wa[7]=f2bf(a1.w);
            *reinterpret_cast<bf16x8*>(&As[r * BK + sg * 8]) = wa;

            const float4* pb = reinterpret_cast<const float4*>(
                Bm + (size_t)(n0 + r) * C_TOT + k0 + g * 8);
            float4 b0 = pb[0], b1 = pb[1];
            bf16x8 wb;
            wb[0]=f2bf(b0.x); wb[1]=f2bf(b0.y); wb[2]=f2bf(b0.z); wb[3]=f2bf(b0.w);
            wb[4]=f2bf(b1.x); wb[5]=f2bf(b1.y); wb[6]=f2bf(b1.z); wb[7]=f2bf(b1.w);
            *reinterpret_cast<bf16x8*>(&Bs[r * BK + sg * 8]) = wb;
        }
        __syncthreads();

        bf16x8 af[4], bfr[4];
        #pragma unroll
        for (int mi = 0; mi < 4; ++mi) {
            const int r  = wr * 64 + mi * 16 + rl;
            const int sg = g_rd ^ ((r >> 1) & 3);
            af[mi] = *reinterpret_cast<const bf16x8*>(&As[r * BK + sg * 8]);
        }
        #pragma unroll
        for (int ni = 0; ni < 4; ++ni) {
            const int r  = wc * 64 + ni * 16 + rl;
            const int sg = g_rd ^ ((r >> 1) & 3);
            bfr[ni] = *reinterpret_cast<const bf16x8*>(&Bs[r * BK + sg * 8]);
        }
        #pragma unroll
        for (int mi = 0; mi < 4; ++mi)
            #pragma unroll
            for (int ni = 0; ni < 4; ++ni)
                acc[mi][ni] = __builtin_amdgcn_mfma_f32_16x16x32_bf16(
                    af[mi], bfr[ni], acc[mi][ni], 0, 0, 0);
        __syncthreads();
    }

    const float inv_c = 1.0f / (float)C_TOT;
    #pragma unroll
    for (int mi = 0; mi < 4; ++mi) {
        #pragma unroll
        for (int i = 0; i < 4; ++i) {
            const int m = m0 + wr * 64 + mi * 16 + (lane >> 4) * 4 + i;
            float s = 0.0f;
            #pragma unroll
            for (int ni = 0; ni < 4; ++ni) {
                const float v = acc[mi][ni][i] * inv_c;
                out[(size_t)m * M_TOT + n0 + wc * 64 + ni * 16 + rl] = v;
                s += v * v;
            }
            s += __shfl_xor(s, 1);
            s += __shfl_xor(s, 2);
            s += __shfl_xor(s, 4);
            s += __shfl_xor(s, 8);
            if (rl == 0) atomicAdd(&penalty[m], s);
        }
    }
}

__global__ __launch_bounds__(256) void scale_k(float* __restrict__ out,
                                               const float* __restrict__ penalty)
{
    const unsigned cols4 = M_TOT / 4;
    const unsigned total = (unsigned)M_TOT * cols4;
    float4* o4 = reinterpret_cast<float4*>(out);
    const float4* p4 = reinterpret_cast<const float4*>(penalty);
    for (unsigned idx = blockIdx.x * blockDim.x + threadIdx.x; idx < total;
         idx += gridDim.x * blockDim.x) {
        const unsigned n4 = idx % cols4;
        const float4 p = p4[n4];
        float4 v = o4[idx];
        v.x *= rsqrtf(p.x);
        v.y *= rsqrtf(p.y);
        v.z *= rsqrtf(p.z);
        v.w *= rsqrtf(p.w);
        o4[idx] = v;
    }
}

// ---------------- launch ----------------

extern "C" void kernel_launch(void* const* d_in, const int* in_sizes, int n_in,
                              void* d_out, int out_size, void* d_ws, size_t ws_size,
                              hipStream_t stream) {
    const float* A = (const float*)d_in[0];
    const float* B = (const float*)d_in[1];
    float* out     = (float*)d_out;

    const size_t mat_sh = (size_t)M_TOT * C_TOT;                   // 1,638,400
    const size_t sz_ab  = mat_sh * sizeof(short);                  // 3,276,800
    const size_t sz_gb  = (size_t)C_TOT * C_TOT * sizeof(short);   // 131,072
    const size_t sz_p   = (size_t)M_TOT * sizeof(float);           // 25,600
    const size_t sz_gp  = (size_t)GK_CHUNKS * C_TOT * C_TOT * sizeof(float); // 5 MB
    const size_t need_full = 3 * sz_ab + sz_gb + sz_p + sz_gp;     // ~15.3 MB
    const size_t need_mid  = 2 * sz_ab + sz_p;                     // ~6.6 MB

    dim3 grid(M_TOT / BN, M_TOT / BM);   // 50 x 50

    if (ws_size >= need_full) {
        short* Ab = (short*)d_ws;
        short* Bb = Ab + mat_sh;
        short* Bt = Bb + mat_sh;
        short* Gb = Bt + mat_sh;
        float* P  = (float*)((char*)d_ws + 3 * sz_ab + sz_gb);
        float* Gp = (float*)((char*)d_ws + 3 * sz_ab + sz_gb + sz_p);

        convert_bf16<<<1600, 256, 0, stream>>>(A, B, Ab, Bb);
        transpose_b<<<dim3(M_TOT / 64, C_TOT / 64), 256, 0, stream>>>(B, Bt);
        gemm_G<<<dim3(2, 2, GK_CHUNKS), 256, 0, stream>>>(Bt, Gp);
        g_reduce<<<64, 256, 0, stream>>>(Gp, Gb);
        penalty_G<<<M_TOT / BM, 256, 0, stream>>>(Ab, Gb, P);
        gemm_out<<<grid, dim3(256), 0, stream>>>(Ab, Bb, P, out);
    } else if (ws_size >= need_mid) {
        short* Ab = (short*)d_ws;
        short* Bb = Ab + mat_sh;
        float* P  = (float*)(Bb + mat_sh);

        hipMemsetAsync(P, 0, sz_p, stream);
        convert_bf16<<<1600, 256, 0, stream>>>(A, B, Ab, Bb);
        gemm_penalty<<<grid, dim3(256), 0, stream>>>(Ab, Bb, P);
        gemm_out<<<grid, dim3(256), 0, stream>>>(Ab, Bb, P, out);
    } else {
        float* penalty = (float*)d_ws;
        hipMemsetAsync(penalty, 0, sz_p, stream);
        corr_gemm<<<grid, dim3(256), 0, stream>>>(A, B, out, penalty);
        scale_k<<<2048, 256, 0, stream>>>(out, penalty);
    }
}

// Round 5
// 89.862 us; speedup vs baseline: 1.5404x; 1.0092x over previous
//
#include <hip/hip_runtime.h>

typedef __attribute__((ext_vector_type(8))) short bf16x8;
typedef __attribute__((ext_vector_type(4))) float f32x4;

#define M_TOT 6400   // 80*80 flattened spatial positions
#define C_TOT 256    // channels (K of the main GEMM)
#define BM 128
#define BN 128
#define BK 32
#define GK_CHUNKS 20           // K-split for Gram kernel: 6400 = 20 * 320
#define GK_STEPS  10           // 320 / 32

#define VMCNT0 asm volatile("s_waitcnt vmcnt(0)" ::: "memory")
#define SBAR   __builtin_amdgcn_s_barrier()

// f32 -> bf16 round-to-nearest-even
__device__ __forceinline__ short f2bf(float f) {
    unsigned u = __float_as_uint(f);
    u = (u + 0x7fffu + ((u >> 16) & 1u)) >> 16;
    return (short)u;
}
__device__ __forceinline__ float bf2f(short s) {
    return __uint_as_float(((unsigned)(unsigned short)s) << 16);
}

// async global->LDS, 16B per lane; LDS dst is wave-uniform base + lane*16
__device__ __forceinline__ void gload16(const short* g, short* l) {
    __builtin_amdgcn_global_load_lds(
        (const __attribute__((address_space(1))) void*)g,
        (__attribute__((address_space(3))) void*)l, 16, 0, 0);
}

// ---------------- conversion / transpose ----------------

__global__ __launch_bounds__(256) void convert_bf16(const float* __restrict__ A,
                                                    const float* __restrict__ Bm,
                                                    short* __restrict__ Ab,
                                                    short* __restrict__ Bb)
{
    const int n8 = M_TOT * C_TOT / 8;   // 204800 chunks of 8 floats per matrix
    for (int i = blockIdx.x * blockDim.x + threadIdx.x; i < 2 * n8;
         i += gridDim.x * blockDim.x) {
        const float* s = (i < n8) ? (A + (size_t)i * 8) : (Bm + (size_t)(i - n8) * 8);
        short* d       = (i < n8) ? (Ab + (size_t)i * 8) : (Bb + (size_t)(i - n8) * 8);
        const float4 v0 = reinterpret_cast<const float4*>(s)[0];
        const float4 v1 = reinterpret_cast<const float4*>(s)[1];
        bf16x8 w;
        w[0]=f2bf(v0.x); w[1]=f2bf(v0.y); w[2]=f2bf(v0.z); w[3]=f2bf(v0.w);
        w[4]=f2bf(v1.x); w[5]=f2bf(v1.y); w[6]=f2bf(v1.z); w[7]=f2bf(v1.w);
        *reinterpret_cast<bf16x8*>(d) = w;
    }
}

// Bt[c][n] = bf16(Bm[n][c]);  64x64 tiles through LDS
__global__ __launch_bounds__(256) void transpose_b(const float* __restrict__ Bm,
                                                   short* __restrict__ Bt)
{
    __shared__ __align__(16) short Lb[64][72];   // +8 pad, 16B-aligned rows
    const int t  = threadIdx.x;
    const int n0 = blockIdx.x * 64;
    const int c0 = blockIdx.y * 64;
    const int r  = t >> 2;
    const int cb = (t & 3) * 16;

    const float4* src = reinterpret_cast<const float4*>(
        Bm + (size_t)(n0 + r) * C_TOT + c0 + cb);
    const float4 v0 = src[0], v1 = src[1], v2 = src[2], v3 = src[3];
    bf16x8 w0, w1;
    w0[0]=f2bf(v0.x); w0[1]=f2bf(v0.y); w0[2]=f2bf(v0.z); w0[3]=f2bf(v0.w);
    w0[4]=f2bf(v1.x); w0[5]=f2bf(v1.y); w0[6]=f2bf(v1.z); w0[7]=f2bf(v1.w);
    w1[0]=f2bf(v2.x); w1[1]=f2bf(v2.y); w1[2]=f2bf(v2.z); w1[3]=f2bf(v2.w);
    w1[4]=f2bf(v3.x); w1[5]=f2bf(v3.y); w1[6]=f2bf(v3.z); w1[7]=f2bf(v3.w);
    *reinterpret_cast<bf16x8*>(&Lb[r][cb])     = w0;
    *reinterpret_cast<bf16x8*>(&Lb[r][cb + 8]) = w1;
    __syncthreads();

    #pragma unroll
    for (int p = 0; p < 2; ++p) {
        const int q = t + p * 256;
        const int c = q >> 3;        // 0..63 output row (channel)
        const int h = q & 7;         // 8-col group
        bf16x8 w;
        #pragma unroll
        for (int j = 0; j < 8; ++j) w[j] = Lb[h * 8 + j][c];
        *reinterpret_cast<bf16x8*>(&Bt[(size_t)(c0 + c) * M_TOT + n0 + h * 8]) = w;
    }
}

// ---------------- generalized 2-phase pipelined 128x128 GEMM tile ----------------
// dot[m,n] = sum_k A[m0+m][kb+k] * B[n0+n][kb+k], both row-major, f32 accum.
// LDS tile layout: [row][4 slots of 8 bf16], slot content XOR-swizzled by row:
// LDS slot (r,g) holds global slot g ^ ((r>>1)&3).  global_load_lds writes
// linearly (rule #21), so the swizzle is applied to the per-lane GLOBAL source
// address; the fragment read applies the same XOR and the involution cancels.
// This balances ds_read_b128 across all 8 bank-quads (was 8-way conflicted).

__device__ __forceinline__ void stage_tiles_g(const short* __restrict__ A,
                                              const short* __restrict__ B,
                                              int m0, int n0, int k0,
                                              int lda, int ldb,
                                              short* As, short* Bs,
                                              int wave, int lane)
{
    #pragma unroll
    for (int t = 0; t < 2; ++t) {
        const int c  = (wave * 2 + t) * 64 + lane;   // 16B-chunk id 0..511
        const int r  = c >> 2;                        // tile row
        const int g  = c & 3;                         // LDS k-slot (8 bf16)
        const int sg = g ^ ((r >> 1) & 3);            // source pre-swizzle
        gload16(A + (size_t)(m0 + r) * lda + k0 + sg * 8, As + (wave * 2 + t) * 512);
        gload16(B + (size_t)(n0 + r) * ldb + k0 + sg * 8, Bs + (wave * 2 + t) * 512);
    }
}

template<int KSTEPS>
__device__ __forceinline__ void gemm_tile_g(const short* __restrict__ A,
                                            const short* __restrict__ B,
                                            int m0, int n0, int kbase,
                                            int lda, int ldb, int tid,
                                            short (*Sm)[2][4096],
                                            f32x4 acc[4][4])
{
    const int lane = tid & 63;
    const int wave = tid >> 6;
    const int rl   = lane & 15;
    const int g_rd = lane >> 4;
    const int wr   = wave >> 1;
    const int wc   = wave & 1;

    stage_tiles_g(A, B, m0, n0, kbase, lda, ldb, &Sm[0][0][0], &Sm[0][1][0], wave, lane);
    VMCNT0; SBAR;

    #pragma unroll
    for (int kt = 0; kt < KSTEPS; ++kt) {
        const int cur = kt & 1;
        if (kt < KSTEPS - 1)
            stage_tiles_g(A, B, m0, n0, kbase + (kt + 1) * BK, lda, ldb,
                          &Sm[cur ^ 1][0][0], &Sm[cur ^ 1][1][0], wave, lane);

        bf16x8 af[4], bfr[4];
        #pragma unroll
        for (int mi = 0; mi < 4; ++mi) {
            const int r  = wr * 64 + mi * 16 + rl;
            const int sg = g_rd ^ ((r >> 1) & 3);     // read-side swizzle
            af[mi] = *reinterpret_cast<const bf16x8*>(&Sm[cur][0][r * BK + sg * 8]);
        }
        #pragma unroll
        for (int ni = 0; ni < 4; ++ni) {
            const int r  = wc * 64 + ni * 16 + rl;
            const int sg = g_rd ^ ((r >> 1) & 3);
            bfr[ni] = *reinterpret_cast<const bf16x8*>(&Sm[cur][1][r * BK + sg * 8]);
        }
        #pragma unroll
        for (int mi = 0; mi < 4; ++mi)
            #pragma unroll
            for (int ni = 0; ni < 4; ++ni)
                acc[mi][ni] = __builtin_amdgcn_mfma_f32_16x16x32_bf16(
                    af[mi], bfr[ni], acc[mi][ni], 0, 0, 0);

        if (kt < KSTEPS - 1) { VMCNT0; SBAR; }
    }
}

// ---------------- Gram path ----------------

// partial G: Gp[z][c][c'] = sum_{n in chunk z} Bt[c][n] * Bt[c'][n]
__global__ __launch_bounds__(256) void gemm_G(const short* __restrict__ Bt,
                                              float* __restrict__ Gp)
{
    __shared__ __align__(16) short Sm[2][2][4096];
    const int tid = threadIdx.x;
    const int m0 = blockIdx.y * BM, n0 = blockIdx.x * BN;
    const int z  = blockIdx.z;
    f32x4 acc[4][4] = {};
    gemm_tile_g<GK_STEPS>(Bt, Bt, m0, n0, z * (M_TOT / GK_CHUNKS),
                          M_TOT, M_TOT, tid, Sm, acc);

    float* dst = Gp + (size_t)z * (C_TOT * C_TOT);
    const int lane = tid & 63, rl = lane & 15;
    const int wave = tid >> 6, wr = wave >> 1, wc = wave & 1;
    #pragma unroll
    for (int mi = 0; mi < 4; ++mi)
        #pragma unroll
        for (int i = 0; i < 4; ++i) {
            const int m = m0 + wr * 64 + mi * 16 + (lane >> 4) * 4 + i;
            #pragma unroll
            for (int ni = 0; ni < 4; ++ni)
                dst[m * C_TOT + n0 + wc * 64 + ni * 16 + rl] = acc[mi][ni][i];
        }
}

// Gb = bf16( sum_z Gp[z] )
__global__ __launch_bounds__(256) void g_reduce(const float* __restrict__ Gp,
                                                short* __restrict__ Gb)
{
    const int i4 = blockIdx.x * 256 + threadIdx.x;   // 16384 float4 groups
    float4 s = make_float4(0.f, 0.f, 0.f, 0.f);
    for (int z = 0; z < GK_CHUNKS; ++z) {
        const float4 v = reinterpret_cast<const float4*>(
            Gp + (size_t)z * (C_TOT * C_TOT))[i4];
        s.x += v.x; s.y += v.y; s.z += v.z; s.w += v.w;
    }
    short4 o;
    o.x = f2bf(s.x); o.y = f2bf(s.y); o.z = f2bf(s.z); o.w = f2bf(s.w);
    reinterpret_cast<short4*>(Gb)[i4] = o;
}

// P[m] = A[m]^T G A[m]  (G symmetric)
__global__ __launch_bounds__(256) void penalty_G(const short* __restrict__ Ab,
                                                 const short* __restrict__ Gb,
                                                 float* __restrict__ P)
{
    __shared__ __align__(16) short Sm[2][2][4096];
    __shared__ float q_lds[BM];
    const int tid = threadIdx.x;
    const int m0 = blockIdx.x * BM;
    const int lane = tid & 63, rl = lane & 15;
    const int wave = tid >> 6, wr = wave >> 1, wc = wave & 1;

    if (tid < BM) q_lds[tid] = 0.0f;
    __syncthreads();

    #pragma unroll
    for (int nt = 0; nt < 2; ++nt) {
        f32x4 acc[4][4] = {};
        gemm_tile_g<8>(Ab, Gb, m0, nt * BN, 0, C_TOT, C_TOT, tid, Sm, acc);
        const int n0 = nt * BN;
        #pragma unroll
        for (int mi = 0; mi < 4; ++mi)
            #pragma unroll
            for (int i = 0; i < 4; ++i) {
                const int m = m0 + wr * 64 + mi * 16 + (lane >> 4) * 4 + i;
                float s = 0.0f;
                #pragma unroll
                for (int ni = 0; ni < 4; ++ni) {
                    const int cp = n0 + wc * 64 + ni * 16 + rl;
                    s += acc[mi][ni][i] * bf2f(Ab[(size_t)m * C_TOT + cp]);
                }
                s += __shfl_xor(s, 1);
                s += __shfl_xor(s, 2);
                s += __shfl_xor(s, 4);
                s += __shfl_xor(s, 8);
                if (rl == 0) atomicAdd(&q_lds[m - m0], s);
            }
    }
    __syncthreads();
    if (tid < BM) P[m0 + tid] = q_lds[tid];
}

// ---------------- output GEMM ----------------

__global__ __launch_bounds__(256) void gemm_out(const short* __restrict__ Ab,
                                                const short* __restrict__ Bb,
                                                const float* __restrict__ P,
                                                float* __restrict__ out)
{
    __shared__ __align__(16) short Sm[2][2][4096];   // 32 KB, reused by epilogue
    const int tid = threadIdx.x;
    const int lane = tid & 63, rl = lane & 15;
    const int wave = tid >> 6, wr = wave >> 1, wc = wave & 1;
    const int m0 = blockIdx.y * BM, n0 = blockIdx.x * BN;

    float rs[4];
    #pragma unroll
    for (int ni = 0; ni < 4; ++ni)
        rs[ni] = rsqrtf(P[n0 + wc * 64 + ni * 16 + rl]);

    f32x4 acc[4][4] = {};
    gemm_tile_g<8>(Ab, Bb, m0, n0, 0, C_TOT, C_TOT, tid, Sm, acc);

    SBAR;   // all waves done with K-loop LDS before epilogue reuse

    // wave-private 16x68 f32 scratch (padded)
    float* Es = reinterpret_cast<float*>(Sm) + wave * 1088;
    #pragma unroll
    for (int mi = 0; mi < 4; ++mi) {
        #pragma unroll
        for (int ni = 0; ni < 4; ++ni)
            #pragma unroll
            for (int i = 0; i < 4; ++i)
                Es[((lane >> 4) * 4 + i) * 68 + ni * 16 + rl] = acc[mi][ni][i] * rs[ni];
        #pragma unroll
        for (int it = 0; it < 4; ++it) {
            const int f   = it * 64 + lane;
            const int row = f >> 4;
            const int c4  = f & 15;
            const float4 v = *reinterpret_cast<const float4*>(&Es[row * 68 + c4 * 4]);
            const int m = m0 + wr * 64 + mi * 16 + row;
            *reinterpret_cast<float4*>(&out[(size_t)m * M_TOT + n0 + wc * 64 + c4 * 4]) = v;
        }
    }
}

// ---------------- mid fallback: two-GEMM ----------------

__global__ __launch_bounds__(256) void gemm_penalty(const short* __restrict__ Ab,
                                                    const short* __restrict__ Bb,
                                                    float* __restrict__ P)
{
    __shared__ __align__(16) short Sm[2][2][4096];
    const int tid = threadIdx.x;
    const int m0 = blockIdx.y * BM, n0 = blockIdx.x * BN;
    f32x4 acc[4][4] = {};
    gemm_tile_g<8>(Ab, Bb, m0, n0, 0, C_TOT, C_TOT, tid, Sm, acc);

    const int lane = tid & 63, rl = lane & 15;
    const int wave = tid >> 6, wr = wave >> 1;
    #pragma unroll
    for (int mi = 0; mi < 4; ++mi) {
        #pragma unroll
        for (int i = 0; i < 4; ++i) {
            const int m = m0 + wr * 64 + mi * 16 + (lane >> 4) * 4 + i;
            float s = 0.0f;
            #pragma unroll
            for (int ni = 0; ni < 4; ++ni) {
                const float v = acc[mi][ni][i];
                s += v * v;
            }
            s += __shfl_xor(s, 1);
            s += __shfl_xor(s, 2);
            s += __shfl_xor(s, 4);
            s += __shfl_xor(s, 8);
            if (rl == 0) atomicAdd(&P[m], s);
        }
    }
}

// ---------------- final fallback (round-1) ----------------

__global__ __launch_bounds__(256) void corr_gemm(const float* __restrict__ A,
                                                 const float* __restrict__ Bm,
                                                 float* __restrict__ out,
                                                 float* __restrict__ penalty)
{
    __shared__ short As[BM * BK];
    __shared__ short Bs[BN * BK];

    const int tid  = threadIdx.x;
    const int lane = tid & 63;
    const int wave = tid >> 6;
    const int wr   = wave >> 1;
    const int wc   = wave & 1;
    const int m0   = blockIdx.y * BM;
    const int n0   = blockIdx.x * BN;
    const int g_rd = lane >> 4;
    const int rl   = lane & 15;

    f32x4 acc[4][4] = {};

    for (int k0 = 0; k0 < C_TOT; k0 += BK) {
        #pragma unroll
        for (int half = 0; half < 2; ++half) {
            const int cc = tid + half * 256;
            const int r  = cc >> 2;
            const int g  = cc & 3;
            const int sg = g ^ ((r >> 1) & 3);

            const float4* pa = reinterpret_cast<const float4*>(
                A + (size_t)(m0 + r) * C_TOT + k0 + g * 8);
            float4 a0 = pa[0], a1 = pa[1];
            bf16x8 wa;
            wa[0]=f2bf(a0.x); wa[1]=f2bf(a0.y); wa[2]=f2bf(a0.z); wa[3]=f2bf(a0.w);
            wa[4]=f2bf(a1.x); wa[5]=f2bf(a1.y); wa[6]=f2bf(a1.z); wa[7]=f2bf(a1.w);
            *reinterpret_cast<bf16x8*>(&As[r * BK + sg * 8]) = wa;

            const float4* pb = reinterpret_cast<const float4*>(
                Bm + (size_t)(n0 + r) * C_TOT + k0 + g * 8);
            float4 b0 = pb[0], b1 = pb[1];
            bf16x8 wb;
            wb[0]=f2bf(b0.x); wb[1]=f2bf(b0.y); wb[2]=f2bf(b0.z); wb[3]=f2bf(b0.w);
            wb[4]=f2bf(b1.x); wb[5]=f2bf(b1.y); wb[6]=f2bf(b1.z); wb[7]=f2bf(b1.w);
            *reinterpret_cast<bf16x8*>(&Bs[r * BK + sg * 8]) = wb;
        }
        __syncthreads();

        bf16x8 af[4], bfr[4];
        #pragma unroll
        for (int mi = 0; mi < 4; ++mi) {
            const int r  = wr * 64 + mi * 16 + rl;
            const int sg = g_rd ^ ((r >> 1) & 3);
            af[mi] = *reinterpret_cast<const bf16x8*>(&As[r * BK + sg * 8]);
        }
        #pragma unroll
        for (int ni = 0; ni < 4; ++ni) {
            const int r  = wc * 64 + ni * 16 + rl;
            const int sg = g_rd ^ ((r >> 1) & 3);
            bfr[ni] = *reinterpret_cast<const bf16x8*>(&Bs[r * BK + sg * 8]);
        }
        #pragma unroll
        for (int mi = 0; mi < 4; ++mi)
            #pragma unroll
            for (int ni = 0; ni < 4; ++ni)
                acc[mi][ni] = __builtin_amdgcn_mfma_f32_16x16x32_bf16(
                    af[mi], bfr[ni], acc[mi][ni], 0, 0, 0);
        __syncthreads();
    }

    const float inv_c = 1.0f / (float)C_TOT;
    #pragma unroll
    for (int mi = 0; mi < 4; ++mi) {
        #pragma unroll
        for (int i = 0; i < 4; ++i) {
            const int m = m0 + wr * 64 + mi * 16 + (lane >> 4) * 4 + i;
            float s = 0.0f;
            #pragma unroll
            for (int ni = 0; ni < 4; ++ni) {
                const float v = acc[mi][ni][i] * inv_c;
                out[(size_t)m * M_TOT + n0 + wc * 64 + ni * 16 + rl] = v;
                s += v * v;
            }
            s += __shfl_xor(s, 1);
            s += __shfl_xor(s, 2);
            s += __shfl_xor(s, 4);
            s += __shfl_xor(s, 8);
            if (rl == 0) atomicAdd(&penalty[m], s);
        }
    }
}

__global__ __launch_bounds__(256) void scale_k(float* __restrict__ out,
                                               const float* __restrict__ penalty)
{
    const unsigned cols4 = M_TOT / 4;
    const unsigned total = (unsigned)M_TOT * cols4;
    float4* o4 = reinterpret_cast<float4*>(out);
    const float4* p4 = reinterpret_cast<const float4*>(penalty);
    for (unsigned idx = blockIdx.x * blockDim.x + threadIdx.x; idx < total;
         idx += gridDim.x * blockDim.x) {
        const unsigned n4 = idx % cols4;
        const float4 p = p4[n4];
        float4 v = o4[idx];
        v.x *= rsqrtf(p.x);
        v.y *= rsqrtf(p.y);
        v.z *= rsqrtf(p.z);
        v.w *= rsqrtf(p.w);
        o4[idx] = v;
    }
}

// ---------------- launch ----------------

extern "C" void kernel_launch(void* const* d_in, const int* in_sizes, int n_in,
                              void* d_out, int out_size, void* d_ws, size_t ws_size,
                              hipStream_t stream) {
    const float* A = (const float*)d_in[0];
    const float* B = (const float*)d_in[1];
    float* out     = (float*)d_out;

    const size_t mat_sh = (size_t)M_TOT * C_TOT;                   // 1,638,400
    const size_t sz_ab  = mat_sh * sizeof(short);                  // 3,276,800
    const size_t sz_gb  = (size_t)C_TOT * C_TOT * sizeof(short);   // 131,072
    const size_t sz_p   = (size_t)M_TOT * sizeof(float);           // 25,600
    const size_t sz_gp  = (size_t)GK_CHUNKS * C_TOT * C_TOT * sizeof(float); // 5 MB
    const size_t need_full = 3 * sz_ab + sz_gb + sz_p + sz_gp;     // ~15.3 MB
    const size_t need_mid  = 2 * sz_ab + sz_p;                     // ~6.6 MB

    dim3 grid(M_TOT / BN, M_TOT / BM);   // 50 x 50

    if (ws_size >= need_full) {
        short* Ab = (short*)d_ws;
        short* Bb = Ab + mat_sh;
        short* Bt = Bb + mat_sh;
        short* Gb = Bt + mat_sh;
        float* P  = (float*)((char*)d_ws + 3 * sz_ab + sz_gb);
        float* Gp = (float*)((char*)d_ws + 3 * sz_ab + sz_gb + sz_p);

        convert_bf16<<<1600, 256, 0, stream>>>(A, B, Ab, Bb);
        transpose_b<<<dim3(M_TOT / 64, C_TOT / 64), 256, 0, stream>>>(B, Bt);
        gemm_G<<<dim3(2, 2, GK_CHUNKS), 256, 0, stream>>>(Bt, Gp);
        g_reduce<<<64, 256, 0, stream>>>(Gp, Gb);
        penalty_G<<<M_TOT / BM, 256, 0, stream>>>(Ab, Gb, P);
        gemm_out<<<grid, dim3(256), 0, stream>>>(Ab, Bb, P, out);
    } else if (ws_size >= need_mid) {
        short* Ab = (short*)d_ws;
        short* Bb = Ab + mat_sh;
        float* P  = (float*)(Bb + mat_sh);

        hipMemsetAsync(P, 0, sz_p, stream);
        convert_bf16<<<1600, 256, 0, stream>>>(A, B, Ab, Bb);
        gemm_penalty<<<grid, dim3(256), 0, stream>>>(Ab, Bb, P);
        gemm_out<<<grid, dim3(256), 0, stream>>>(Ab, Bb, P, out);
    } else {
        float* penalty = (float*)d_ws;
        hipMemsetAsync(penalty, 0, sz_p, stream);
        corr_gemm<<<grid, dim3(256), 0, stream>>>(A, B, out, penalty);
        scale_k<<<2048, 256, 0, stream>>>(out, penalty);
    }
}

// Round 6
// 85.518 us; speedup vs baseline: 1.6187x; 1.0508x over previous
//
#include <hip/hip_runtime.h>

typedef __attribute__((ext_vector_type(8))) short bf16x8;
typedef __attribute__((ext_vector_type(4))) float f32x4;

#define M_TOT 6400   // 80*80 flattened spatial positions
#define C_TOT 256    // channels (K of the main GEMM)
#define BM 128
#define BN 128
#define BK 32
#define NTILE 50     // 6400 / 128
#define GK_CHUNKS 20           // K-split for Gram kernel: 6400 = 20 * 320
#define GK_STEPS  10           // 320 / 32

#define VMCNT0 asm volatile("s_waitcnt vmcnt(0)" ::: "memory")
#define VMCNT4 asm volatile("s_waitcnt vmcnt(4)" ::: "memory")
#define SBAR   __builtin_amdgcn_s_barrier()

// f32 -> bf16 round-to-nearest-even
__device__ __forceinline__ short f2bf(float f) {
    unsigned u = __float_as_uint(f);
    u = (u + 0x7fffu + ((u >> 16) & 1u)) >> 16;
    return (short)u;
}
__device__ __forceinline__ float bf2f(short s) {
    return __uint_as_float(((unsigned)(unsigned short)s) << 16);
}

// async global->LDS, 16B per lane; LDS dst is wave-uniform base + lane*16
__device__ __forceinline__ void gload16(const short* g, short* l) {
    __builtin_amdgcn_global_load_lds(
        (const __attribute__((address_space(1))) void*)g,
        (__attribute__((address_space(3))) void*)l, 16, 0, 0);
}

// ---------------- conversion / transpose ----------------

// A only (full path)
__global__ __launch_bounds__(256) void convert_a(const float* __restrict__ A,
                                                 short* __restrict__ Ab)
{
    const int n8 = M_TOT * C_TOT / 8;
    for (int i = blockIdx.x * blockDim.x + threadIdx.x; i < n8;
         i += gridDim.x * blockDim.x) {
        const float4 v0 = reinterpret_cast<const float4*>(A + (size_t)i * 8)[0];
        const float4 v1 = reinterpret_cast<const float4*>(A + (size_t)i * 8)[1];
        bf16x8 w;
        w[0]=f2bf(v0.x); w[1]=f2bf(v0.y); w[2]=f2bf(v0.z); w[3]=f2bf(v0.w);
        w[4]=f2bf(v1.x); w[5]=f2bf(v1.y); w[6]=f2bf(v1.z); w[7]=f2bf(v1.w);
        *reinterpret_cast<bf16x8*>(Ab + (size_t)i * 8) = w;
    }
}

// A and B (mid fallback path)
__global__ __launch_bounds__(256) void convert_ab(const float* __restrict__ A,
                                                  const float* __restrict__ Bm,
                                                  short* __restrict__ Ab,
                                                  short* __restrict__ Bb)
{
    const int n8 = M_TOT * C_TOT / 8;
    for (int i = blockIdx.x * blockDim.x + threadIdx.x; i < 2 * n8;
         i += gridDim.x * blockDim.x) {
        const float* s = (i < n8) ? (A + (size_t)i * 8) : (Bm + (size_t)(i - n8) * 8);
        short* d       = (i < n8) ? (Ab + (size_t)i * 8) : (Bb + (size_t)(i - n8) * 8);
        const float4 v0 = reinterpret_cast<const float4*>(s)[0];
        const float4 v1 = reinterpret_cast<const float4*>(s)[1];
        bf16x8 w;
        w[0]=f2bf(v0.x); w[1]=f2bf(v0.y); w[2]=f2bf(v0.z); w[3]=f2bf(v0.w);
        w[4]=f2bf(v1.x); w[5]=f2bf(v1.y); w[6]=f2bf(v1.z); w[7]=f2bf(v1.w);
        *reinterpret_cast<bf16x8*>(d) = w;
    }
}

// reads B f32 once; writes Bb[n][c] (row-major bf16) AND Bt[c][n] (transposed)
__global__ __launch_bounds__(256) void trans_b(const float* __restrict__ Bm,
                                               short* __restrict__ Bb,
                                               short* __restrict__ Bt)
{
    __shared__ __align__(16) short Lb[64][72];   // +8 pad
    const int t  = threadIdx.x;
    const int n0 = blockIdx.x * 64;
    const int c0 = blockIdx.y * 64;
    const int r  = t >> 2;
    const int cb = (t & 3) * 16;

    const float4* src = reinterpret_cast<const float4*>(
        Bm + (size_t)(n0 + r) * C_TOT + c0 + cb);
    const float4 v0 = src[0], v1 = src[1], v2 = src[2], v3 = src[3];
    bf16x8 w0, w1;
    w0[0]=f2bf(v0.x); w0[1]=f2bf(v0.y); w0[2]=f2bf(v0.z); w0[3]=f2bf(v0.w);
    w0[4]=f2bf(v1.x); w0[5]=f2bf(v1.y); w0[6]=f2bf(v1.z); w0[7]=f2bf(v1.w);
    w1[0]=f2bf(v2.x); w1[1]=f2bf(v2.y); w1[2]=f2bf(v2.z); w1[3]=f2bf(v2.w);
    w1[4]=f2bf(v3.x); w1[5]=f2bf(v3.y); w1[6]=f2bf(v3.z); w1[7]=f2bf(v3.w);
    *reinterpret_cast<bf16x8*>(&Lb[r][cb])     = w0;
    *reinterpret_cast<bf16x8*>(&Lb[r][cb + 8]) = w1;
    // row-major copy while we have the values in registers
    short* brow = Bb + (size_t)(n0 + r) * C_TOT + c0 + cb;
    *reinterpret_cast<bf16x8*>(brow)     = w0;
    *reinterpret_cast<bf16x8*>(brow + 8) = w1;
    __syncthreads();

    #pragma unroll
    for (int p = 0; p < 2; ++p) {
        const int q = t + p * 256;
        const int c = q >> 3;        // 0..63 output row (channel)
        const int h = q & 7;         // 8-col group
        bf16x8 w;
        #pragma unroll
        for (int j = 0; j < 8; ++j) w[j] = Lb[h * 8 + j][c];
        *reinterpret_cast<bf16x8*>(&Bt[(size_t)(c0 + c) * M_TOT + n0 + h * 8]) = w;
    }
}

// ------- 3-buffer, 2-deep-prefetch, counted-vmcnt 128x128 GEMM tile (T4) -------
// dot[m,n] = sum_k A[m0+m][kb+k] * B[n0+n][kb+k], both row-major, f32 accum.
// Sm = [3 buffers][A/B][4096 shorts].  Each stage issues 4 global_load_lds per
// thread; steady-state waits vmcnt(4): tile t+1 retired, t+2 still in flight.
// K-slot content XOR-swizzled by row (source-side pre-swizzle, rule #21).

__device__ __forceinline__ void stage_tiles_g(const short* __restrict__ A,
                                              const short* __restrict__ B,
                                              int m0, int n0, int k0,
                                              int lda, int ldb,
                                              short* As, short* Bs,
                                              int wave, int lane)
{
    #pragma unroll
    for (int t = 0; t < 2; ++t) {
        const int c  = (wave * 2 + t) * 64 + lane;   // 16B-chunk id 0..511
        const int r  = c >> 2;                        // tile row
        const int g  = c & 3;                         // LDS k-slot (8 bf16)
        const int sg = g ^ ((r >> 1) & 3);            // source pre-swizzle
        gload16(A + (size_t)(m0 + r) * lda + k0 + sg * 8, As + (wave * 2 + t) * 512);
        gload16(B + (size_t)(n0 + r) * ldb + k0 + sg * 8, Bs + (wave * 2 + t) * 512);
    }
}

template<int KSTEPS>
__device__ __forceinline__ void gemm_tile_g(const short* __restrict__ A,
                                            const short* __restrict__ B,
                                            int m0, int n0, int kbase,
                                            int lda, int ldb, int tid,
                                            short (*Sm)[2][4096],
                                            f32x4 acc[4][4])
{
    const int lane = tid & 63;
    const int wave = tid >> 6;
    const int rl   = lane & 15;
    const int g_rd = lane >> 4;
    const int wr   = wave >> 1;
    const int wc   = wave & 1;

    // prologue: two tiles in flight
    stage_tiles_g(A, B, m0, n0, kbase, lda, ldb, &Sm[0][0][0], &Sm[0][1][0], wave, lane);
    if (KSTEPS > 1)
        stage_tiles_g(A, B, m0, n0, kbase + BK, lda, ldb,
                      &Sm[1][0][0], &Sm[1][1][0], wave, lane);
    if (KSTEPS > 1) { VMCNT4; } else { VMCNT0; }
    SBAR;

    #pragma unroll
    for (int kt = 0; kt < KSTEPS; ++kt) {
        const int cur = kt % 3;
        if (kt + 2 < KSTEPS)
            stage_tiles_g(A, B, m0, n0, kbase + (kt + 2) * BK, lda, ldb,
                          &Sm[(kt + 2) % 3][0][0], &Sm[(kt + 2) % 3][1][0], wave, lane);

        bf16x8 af[4], bfr[4];
        #pragma unroll
        for (int mi = 0; mi < 4; ++mi) {
            const int r  = wr * 64 + mi * 16 + rl;
            const int sg = g_rd ^ ((r >> 1) & 3);     // read-side swizzle
            af[mi] = *reinterpret_cast<const bf16x8*>(&Sm[cur][0][r * BK + sg * 8]);
        }
        #pragma unroll
        for (int ni = 0; ni < 4; ++ni) {
            const int r  = wc * 64 + ni * 16 + rl;
            const int sg = g_rd ^ ((r >> 1) & 3);
            bfr[ni] = *reinterpret_cast<const bf16x8*>(&Sm[cur][1][r * BK + sg * 8]);
        }
        #pragma unroll
        for (int mi = 0; mi < 4; ++mi)
            #pragma unroll
            for (int ni = 0; ni < 4; ++ni)
                acc[mi][ni] = __builtin_amdgcn_mfma_f32_16x16x32_bf16(
                    af[mi], bfr[ni], acc[mi][ni], 0, 0, 0);

        if (kt + 1 < KSTEPS) {
            if (kt + 2 < KSTEPS) { VMCNT4; } else { VMCNT0; }
            SBAR;
        }
    }
}

// ---------------- Gram path ----------------

// partial G: Gp[z][c][c'] = sum_{n in chunk z} Bt[c][n] * Bt[c'][n]
__global__ __launch_bounds__(256) void gemm_G(const short* __restrict__ Bt,
                                              float* __restrict__ Gp)
{
    __shared__ __align__(16) short Sm[3][2][4096];
    const int tid = threadIdx.x;
    const int m0 = blockIdx.y * BM, n0 = blockIdx.x * BN;
    const int z  = blockIdx.z;
    f32x4 acc[4][4] = {};
    gemm_tile_g<GK_STEPS>(Bt, Bt, m0, n0, z * (M_TOT / GK_CHUNKS),
                          M_TOT, M_TOT, tid, Sm, acc);

    float* dst = Gp + (size_t)z * (C_TOT * C_TOT);
    const int lane = tid & 63, rl = lane & 15;
    const int wave = tid >> 6, wr = wave >> 1, wc = wave & 1;
    #pragma unroll
    for (int mi = 0; mi < 4; ++mi)
        #pragma unroll
        for (int i = 0; i < 4; ++i) {
            const int m = m0 + wr * 64 + mi * 16 + (lane >> 4) * 4 + i;
            #pragma unroll
            for (int ni = 0; ni < 4; ++ni)
                dst[m * C_TOT + n0 + wc * 64 + ni * 16 + rl] = acc[mi][ni][i];
        }
}

// Gb = bf16( sum_z Gp[z] )
__global__ __launch_bounds__(256) void g_reduce(const float* __restrict__ Gp,
                                                short* __restrict__ Gb)
{
    const int i4 = blockIdx.x * 256 + threadIdx.x;   // 16384 float4 groups
    float4 s = make_float4(0.f, 0.f, 0.f, 0.f);
    for (int z = 0; z < GK_CHUNKS; ++z) {
        const float4 v = reinterpret_cast<const float4*>(
            Gp + (size_t)z * (C_TOT * C_TOT))[i4];
        s.x += v.x; s.y += v.y; s.z += v.z; s.w += v.w;
    }
    short4 o;
    o.x = f2bf(s.x); o.y = f2bf(s.y); o.z = f2bf(s.z); o.w = f2bf(s.w);
    reinterpret_cast<short4*>(Gb)[i4] = o;
}

// P[m] = A[m]^T G A[m]  (G symmetric)
__global__ __launch_bounds__(256) void penalty_G(const short* __restrict__ Ab,
                                                 const short* __restrict__ Gb,
                                                 float* __restrict__ P)
{
    __shared__ __align__(16) short Sm[3][2][4096];
    __shared__ float q_lds[BM];
    const int tid = threadIdx.x;
    const int m0 = blockIdx.x * BM;
    const int lane = tid & 63, rl = lane & 15;
    const int wave = tid >> 6, wr = wave >> 1, wc = wave & 1;

    if (tid < BM) q_lds[tid] = 0.0f;
    __syncthreads();

    #pragma unroll
    for (int nt = 0; nt < 2; ++nt) {
        f32x4 acc[4][4] = {};
        gemm_tile_g<8>(Ab, Gb, m0, nt * BN, 0, C_TOT, C_TOT, tid, Sm, acc);
        const int n0 = nt * BN;
        #pragma unroll
        for (int mi = 0; mi < 4; ++mi)
            #pragma unroll
            for (int i = 0; i < 4; ++i) {
                const int m = m0 + wr * 64 + mi * 16 + (lane >> 4) * 4 + i;
                float s = 0.0f;
                #pragma unroll
                for (int ni = 0; ni < 4; ++ni) {
                    const int cp = n0 + wc * 64 + ni * 16 + rl;
                    s += acc[mi][ni][i] * bf2f(Ab[(size_t)m * C_TOT + cp]);
                }
                s += __shfl_xor(s, 1);
                s += __shfl_xor(s, 2);
                s += __shfl_xor(s, 4);
                s += __shfl_xor(s, 8);
                if (rl == 0) atomicAdd(&q_lds[m - m0], s);
            }
        __syncthreads();   // protect Sm reuse between the two nt passes
    }
    if (tid < BM) P[m0 + tid] = q_lds[tid];
}

// ---------------- output GEMM (T1 bijective XCD-chunked swizzle) ----------------

__global__ __launch_bounds__(256) void gemm_out(const short* __restrict__ Ab,
                                                const short* __restrict__ Bb,
                                                const float* __restrict__ P,
                                                float* __restrict__ out)
{
    __shared__ __align__(16) short Sm[3][2][4096];   // 48 KB, reused by epilogue
    const int tid = threadIdx.x;
    const int lane = tid & 63, rl = lane & 15;
    const int wave = tid >> 6, wr = wave >> 1, wc = wave & 1;

    // bijective chunked XCD swizzle (m204): 2500 blocks, 8 XCDs
    const int nwg = NTILE * NTILE, q = nwg >> 3, r = nwg & 7;   // 312, 4
    const int orig = blockIdx.x;
    const int xcd = orig & 7, idx = orig >> 3;
    const int wg = (xcd < r ? xcd * (q + 1) : r * (q + 1) + (xcd - r) * q) + idx;
    const int m0 = (wg / NTILE) * BM;   // chunk is contiguous in by -> A-panel reuse
    const int n0 = (wg % NTILE) * BN;

    float rs[4];
    #pragma unroll
    for (int ni = 0; ni < 4; ++ni)
        rs[ni] = rsqrtf(P[n0 + wc * 64 + ni * 16 + rl]);

    f32x4 acc[4][4] = {};
    gemm_tile_g<8>(Ab, Bb, m0, n0, 0, C_TOT, C_TOT, tid, Sm, acc);

    SBAR;   // all waves done with K-loop LDS before epilogue reuse

    // wave-private 16x68 f32 scratch (padded)
    float* Es = reinterpret_cast<float*>(Sm) + wave * 1088;
    #pragma unroll
    for (int mi = 0; mi < 4; ++mi) {
        #pragma unroll
        for (int ni = 0; ni < 4; ++ni)
            #pragma unroll
            for (int i = 0; i < 4; ++i)
                Es[((lane >> 4) * 4 + i) * 68 + ni * 16 + rl] = acc[mi][ni][i] * rs[ni];
        #pragma unroll
        for (int it = 0; it < 4; ++it) {
            const int f   = it * 64 + lane;
            const int row = f >> 4;
            const int c4  = f & 15;
            const float4 v = *reinterpret_cast<const float4*>(&Es[row * 68 + c4 * 4]);
            const int m = m0 + wr * 64 + mi * 16 + row;
            *reinterpret_cast<float4*>(&out[(size_t)m * M_TOT + n0 + wc * 64 + c4 * 4]) = v;
        }
    }
}

// ---------------- mid fallback: two-GEMM ----------------

__global__ __launch_bounds__(256) void gemm_penalty(const short* __restrict__ Ab,
                                                    const short* __restrict__ Bb,
                                                    float* __restrict__ P)
{
    __shared__ __align__(16) short Sm[3][2][4096];
    const int tid = threadIdx.x;
    const int m0 = blockIdx.y * BM, n0 = blockIdx.x * BN;
    f32x4 acc[4][4] = {};
    gemm_tile_g<8>(Ab, Bb, m0, n0, 0, C_TOT, C_TOT, tid, Sm, acc);

    const int lane = tid & 63, rl = lane & 15;
    const int wave = tid >> 6, wr = wave >> 1;
    #pragma unroll
    for (int mi = 0; mi < 4; ++mi) {
        #pragma unroll
        for (int i = 0; i < 4; ++i) {
            const int m = m0 + wr * 64 + mi * 16 + (lane >> 4) * 4 + i;
            float s = 0.0f;
            #pragma unroll
            for (int ni = 0; ni < 4; ++ni) {
                const float v = acc[mi][ni][i];
                s += v * v;
            }
            s += __shfl_xor(s, 1);
            s += __shfl_xor(s, 2);
            s += __shfl_xor(s, 4);
            s += __shfl_xor(s, 8);
            if (rl == 0) atomicAdd(&P[m], s);
        }
    }
}

// same output kernel without swizzle (plain 2D grid) for the mid path
__global__ __launch_bounds__(256) void gemm_out_plain(const short* __restrict__ Ab,
                                                      const short* __restrict__ Bb,
                                                      const float* __restrict__ P,
                                                      float* __restrict__ out)
{
    __shared__ __align__(16) short Sm[3][2][4096];
    const int tid = threadIdx.x;
    const int lane = tid & 63, rl = lane & 15;
    const int wave = tid >> 6, wr = wave >> 1, wc = wave & 1;
    const int m0 = blockIdx.y * BM, n0 = blockIdx.x * BN;

    float rs[4];
    #pragma unroll
    for (int ni = 0; ni < 4; ++ni)
        rs[ni] = rsqrtf(P[n0 + wc * 64 + ni * 16 + rl]);

    f32x4 acc[4][4] = {};
    gemm_tile_g<8>(Ab, Bb, m0, n0, 0, C_TOT, C_TOT, tid, Sm, acc);

    SBAR;

    float* Es = reinterpret_cast<float*>(Sm) + wave * 1088;
    #pragma unroll
    for (int mi = 0; mi < 4; ++mi) {
        #pragma unroll
        for (int ni = 0; ni < 4; ++ni)
            #pragma unroll
            for (int i = 0; i < 4; ++i)
                Es[((lane >> 4) * 4 + i) * 68 + ni * 16 + rl] = acc[mi][ni][i] * rs[ni];
        #pragma unroll
        for (int it = 0; it < 4; ++it) {
            const int f   = it * 64 + lane;
            const int row = f >> 4;
            const int c4  = f & 15;
            const float4 v = *reinterpret_cast<const float4*>(&Es[row * 68 + c4 * 4]);
            const int m = m0 + wr * 64 + mi * 16 + row;
            *reinterpret_cast<float4*>(&out[(size_t)m * M_TOT + n0 + wc * 64 + c4 * 4]) = v;
        }
    }
}

// ---------------- final fallback (round-1) ----------------

__global__ __launch_bounds__(256) void corr_gemm(const float* __restrict__ A,
                                                 const float* __restrict__ Bm,
                                                 float* __restrict__ out,
                                                 float* __restrict__ penalty)
{
    __shared__ short As[BM * BK];
    __shared__ short Bs[BN * BK];

    const int tid  = threadIdx.x;
    const int lane = tid & 63;
    const int wave = tid >> 6;
    const int wr   = wave >> 1;
    const int wc   = wave & 1;
    const int m0   = blockIdx.y * BM;
    const int n0   = blockIdx.x * BN;
    const int g_rd = lane >> 4;
    const int rl   = lane & 15;

    f32x4 acc[4][4] = {};

    for (int k0 = 0; k0 < C_TOT; k0 += BK) {
        #pragma unroll
        for (int half = 0; half < 2; ++half) {
            const int cc = tid + half * 256;
            const int r  = cc >> 2;
            const int g  = cc & 3;
            const int sg = g ^ ((r >> 1) & 3);

            const float4* pa = reinterpret_cast<const float4*>(
                A + (size_t)(m0 + r) * C_TOT + k0 + g * 8);
            float4 a0 = pa[0], a1 = pa[1];
            bf16x8 wa;
            wa[0]=f2bf(a0.x); wa[1]=f2bf(a0.y); wa[2]=f2bf(a0.z); wa[3]=f2bf(a0.w);
            wa[4]=f2bf(a1.x); wa[5]=f2bf(a1.y); wa[6]=f2bf(a1.z); wa[7]=f2bf(a1.w);
            *reinterpret_cast<bf16x8*>(&As[r * BK + sg * 8]) = wa;

            const float4* pb = reinterpret_cast<const float4*>(
                Bm + (size_t)(n0 + r) * C_TOT + k0 + g * 8);
            float4 b0 = pb[0], b1 = pb[1];
            bf16x8 wb;
            wb[0]=f2bf(b0.x); wb[1]=f2bf(b0.y); wb[2]=f2bf(b0.z); wb[3]=f2bf(b0.w);
            wb[4]=f2bf(b1.x); wb[5]=f2bf(b1.y); wb[6]=f2bf(b1.z); wb[7]=f2bf(b1.w);
            *reinterpret_cast<bf16x8*>(&Bs[r * BK + sg * 8]) = wb;
        }
        __syncthreads();

        bf16x8 af[4], bfr[4];
        #pragma unroll
        for (int mi = 0; mi < 4; ++mi) {
            const int r  = wr * 64 + mi * 16 + rl;
            const int sg = g_rd ^ ((r >> 1) & 3);
            af[mi] = *reinterpret_cast<const bf16x8*>(&As[r * BK + sg * 8]);
        }
        #pragma unroll
        for (int ni = 0; ni < 4; ++ni) {
            const int r  = wc * 64 + ni * 16 + rl;
            const int sg = g_rd ^ ((r >> 1) & 3);
            bfr[ni] = *reinterpret_cast<const bf16x8*>(&Bs[r * BK + sg * 8]);
        }
        #pragma unroll
        for (int mi = 0; mi < 4; ++mi)
            #pragma unroll
            for (int ni = 0; ni < 4; ++ni)
                acc[mi][ni] = __builtin_amdgcn_mfma_f32_16x16x32_bf16(
                    af[mi], bfr[ni], acc[mi][ni], 0, 0, 0);
        __syncthreads();
    }

    const float inv_c = 1.0f / (float)C_TOT;
    #pragma unroll
    for (int mi = 0; mi < 4; ++mi) {
        #pragma unroll
        for (int i = 0; i < 4; ++i) {
            const int m = m0 + wr * 64 + mi * 16 + (lane >> 4) * 4 + i;
            float s = 0.0f;
            #pragma unroll
            for (int ni = 0; ni < 4; ++ni) {
                const float v = acc[mi][ni][i] * inv_c;
                out[(size_t)m * M_TOT + n0 + wc * 64 + ni * 16 + rl] = v;
                s += v * v;
            }
            s += __shfl_xor(s, 1);
            s += __shfl_xor(s, 2);
            s += __shfl_xor(s, 4);
            s += __shfl_xor(s, 8);
            if (rl == 0) atomicAdd(&penalty[m], s);
        }
    }
}

__global__ __launch_bounds__(256) void scale_k(float* __restrict__ out,
                                               const float* __restrict__ penalty)
{
    const unsigned cols4 = M_TOT / 4;
    const unsigned total = (unsigned)M_TOT * cols4;
    float4* o4 = reinterpret_cast<float4*>(out);
    const float4* p4 = reinterpret_cast<const float4*>(penalty);
    for (unsigned idx = blockIdx.x * blockDim.x + threadIdx.x; idx < total;
         idx += gridDim.x * blockDim.x) {
        const unsigned n4 = idx % cols4;
        const float4 p = p4[n4];
        float4 v = o4[idx];
        v.x *= rsqrtf(p.x);
        v.y *= rsqrtf(p.y);
        v.z *= rsqrtf(p.z);
        v.w *= rsqrtf(p.w);
        o4[idx] = v;
    }
}

// ---------------- launch ----------------

extern "C" void kernel_launch(void* const* d_in, const int* in_sizes, int n_in,
                              void* d_out, int out_size, void* d_ws, size_t ws_size,
                              hipStream_t stream) {
    const float* A = (const float*)d_in[0];
    const float* B = (const float*)d_in[1];
    float* out     = (float*)d_out;

    const size_t mat_sh = (size_t)M_TOT * C_TOT;                   // 1,638,400
    const size_t sz_ab  = mat_sh * sizeof(short);                  // 3,276,800
    const size_t sz_gb  = (size_t)C_TOT * C_TOT * sizeof(short);   // 131,072
    const size_t sz_p   = (size_t)M_TOT * sizeof(float);           // 25,600
    const size_t sz_gp  = (size_t)GK_CHUNKS * C_TOT * C_TOT * sizeof(float); // 5 MB
    const size_t need_full = 3 * sz_ab + sz_gb + sz_p + sz_gp;     // ~15.3 MB
    const size_t need_mid  = 2 * sz_ab + sz_p;                     // ~6.6 MB

    dim3 grid2(NTILE, NTILE);   // 50 x 50

    if (ws_size >= need_full) {
        short* Ab = (short*)d_ws;
        short* Bb = Ab + mat_sh;
        short* Bt = Bb + mat_sh;
        short* Gb = Bt + mat_sh;
        float* P  = (float*)((char*)d_ws + 3 * sz_ab + sz_gb);
        float* Gp = (float*)((char*)d_ws + 3 * sz_ab + sz_gb + sz_p);

        convert_a<<<800, 256, 0, stream>>>(A, Ab);
        trans_b<<<dim3(M_TOT / 64, C_TOT / 64), 256, 0, stream>>>(B, Bb, Bt);
        gemm_G<<<dim3(2, 2, GK_CHUNKS), 256, 0, stream>>>(Bt, Gp);
        g_reduce<<<64, 256, 0, stream>>>(Gp, Gb);
        penalty_G<<<M_TOT / BM, 256, 0, stream>>>(Ab, Gb, P);
        gemm_out<<<NTILE * NTILE, 256, 0, stream>>>(Ab, Bb, P, out);
    } else if (ws_size >= need_mid) {
        short* Ab = (short*)d_ws;
        short* Bb = Ab + mat_sh;
        float* P  = (float*)(Bb + mat_sh);

        hipMemsetAsync(P, 0, sz_p, stream);
        convert_ab<<<1600, 256, 0, stream>>>(A, B, Ab, Bb);
        gemm_penalty<<<grid2, dim3(256), 0, stream>>>(Ab, Bb, P);
        gemm_out_plain<<<grid2, dim3(256), 0, stream>>>(Ab, Bb, P, out);
    } else {
        float* penalty = (float*)d_ws;
        hipMemsetAsync(penalty, 0, sz_p, stream);
        corr_gemm<<<grid2, dim3(256), 0, stream>>>(A, B, out, penalty);
        scale_k<<<2048, 256, 0, stream>>>(out, penalty);
    }
}

// Round 7
// 85.009 us; speedup vs baseline: 1.6284x; 1.0060x over previous
//
#include <hip/hip_runtime.h>

typedef __attribute__((ext_vector_type(8))) short bf16x8;
typedef __attribute__((ext_vector_type(4))) float f32x4;

#define M_TOT 6400   // 80*80 flattened spatial positions
#define C_TOT 256    // channels (K of the main GEMM)
#define BM 128
#define BN 128
#define BK 32
#define NTILE 50     // 6400 / 128

#define VMCNT0 asm volatile("s_waitcnt vmcnt(0)" ::: "memory")
#define VMCNT4 asm volatile("s_waitcnt vmcnt(4)" ::: "memory")
#define SBAR   __builtin_amdgcn_s_barrier()

// f32 -> bf16 round-to-nearest-even
__device__ __forceinline__ short f2bf(float f) {
    unsigned u = __float_as_uint(f);
    u = (u + 0x7fffu + ((u >> 16) & 1u)) >> 16;
    return (short)u;
}
__device__ __forceinline__ float bf2f(short s) {
    return __uint_as_float(((unsigned)(unsigned short)s) << 16);
}

// async global->LDS, 16B per lane; LDS dst is wave-uniform base + lane*16
__device__ __forceinline__ void gload16(const short* g, short* l) {
    __builtin_amdgcn_global_load_lds(
        (const __attribute__((address_space(1))) void*)g,
        (__attribute__((address_space(3))) void*)l, 16, 0, 0);
}

// ---------------- fused prep: A->Ab, B->(Bb,Bt), zero P ----------------
// blocks [0,400): B 64x64 tiles (write Bb row-major + Bt transposed)
// blocks [400,500): A bf16 conversion; block 400 also zeroes P.

__global__ __launch_bounds__(256) void prep(const float* __restrict__ A,
                                            const float* __restrict__ Bm,
                                            short* __restrict__ Ab,
                                            short* __restrict__ Bb,
                                            short* __restrict__ Bt,
                                            float* __restrict__ P)
{
    __shared__ __align__(16) short Lb[64][72];
    const int bid = blockIdx.x;
    const int t   = threadIdx.x;

    if (bid < 400) {
        const int n0 = (bid % 100) * 64;
        const int c0 = (bid / 100) * 64;
        const int r  = t >> 2;
        const int cb = (t & 3) * 16;

        const float4* src = reinterpret_cast<const float4*>(
            Bm + (size_t)(n0 + r) * C_TOT + c0 + cb);
        const float4 v0 = src[0], v1 = src[1], v2 = src[2], v3 = src[3];
        bf16x8 w0, w1;
        w0[0]=f2bf(v0.x); w0[1]=f2bf(v0.y); w0[2]=f2bf(v0.z); w0[3]=f2bf(v0.w);
        w0[4]=f2bf(v1.x); w0[5]=f2bf(v1.y); w0[6]=f2bf(v1.z); w0[7]=f2bf(v1.w);
        w1[0]=f2bf(v2.x); w1[1]=f2bf(v2.y); w1[2]=f2bf(v2.z); w1[3]=f2bf(v2.w);
        w1[4]=f2bf(v3.x); w1[5]=f2bf(v3.y); w1[6]=f2bf(v3.z); w1[7]=f2bf(v3.w);
        *reinterpret_cast<bf16x8*>(&Lb[r][cb])     = w0;
        *reinterpret_cast<bf16x8*>(&Lb[r][cb + 8]) = w1;
        short* brow = Bb + (size_t)(n0 + r) * C_TOT + c0 + cb;
        *reinterpret_cast<bf16x8*>(brow)     = w0;
        *reinterpret_cast<bf16x8*>(brow + 8) = w1;
        __syncthreads();

        #pragma unroll
        for (int p = 0; p < 2; ++p) {
            const int q = t + p * 256;
            const int c = q >> 3;
            const int h = q & 7;
            bf16x8 w;
            #pragma unroll
            for (int j = 0; j < 8; ++j) w[j] = Lb[h * 8 + j][c];
            *reinterpret_cast<bf16x8*>(&Bt[(size_t)(c0 + c) * M_TOT + n0 + h * 8]) = w;
        }
    } else {
        const int aid = bid - 400;   // 0..99
        if (aid == 0)
            for (int j = t; j < M_TOT; j += 256) P[j] = 0.0f;
        const int base = aid * 2048;   // 204800 chunks / 100 blocks
        #pragma unroll
        for (int it = 0; it < 8; ++it) {
            const int i = base + it * 256 + t;
            const float4 v0 = reinterpret_cast<const float4*>(A + (size_t)i * 8)[0];
            const float4 v1 = reinterpret_cast<const float4*>(A + (size_t)i * 8)[1];
            bf16x8 w;
            w[0]=f2bf(v0.x); w[1]=f2bf(v0.y); w[2]=f2bf(v0.z); w[3]=f2bf(v0.w);
            w[4]=f2bf(v1.x); w[5]=f2bf(v1.y); w[6]=f2bf(v1.z); w[7]=f2bf(v1.w);
            *reinterpret_cast<bf16x8*>(Ab + (size_t)i * 8) = w;
        }
    }
}

// A and B (mid fallback path)
__global__ __launch_bounds__(256) void convert_ab(const float* __restrict__ A,
                                                  const float* __restrict__ Bm,
                                                  short* __restrict__ Ab,
                                                  short* __restrict__ Bb)
{
    const int n8 = M_TOT * C_TOT / 8;
    for (int i = blockIdx.x * blockDim.x + threadIdx.x; i < 2 * n8;
         i += gridDim.x * blockDim.x) {
        const float* s = (i < n8) ? (A + (size_t)i * 8) : (Bm + (size_t)(i - n8) * 8);
        short* d       = (i < n8) ? (Ab + (size_t)i * 8) : (Bb + (size_t)(i - n8) * 8);
        const float4 v0 = reinterpret_cast<const float4*>(s)[0];
        const float4 v1 = reinterpret_cast<const float4*>(s)[1];
        bf16x8 w;
        w[0]=f2bf(v0.x); w[1]=f2bf(v0.y); w[2]=f2bf(v0.z); w[3]=f2bf(v0.w);
        w[4]=f2bf(v1.x); w[5]=f2bf(v1.y); w[6]=f2bf(v1.z); w[7]=f2bf(v1.w);
        *reinterpret_cast<bf16x8*>(d) = w;
    }
}

// ------- 3-buffer, 2-deep-prefetch, counted-vmcnt 128x128 GEMM tile -------
// dot[m,n] = sum_k A[m0+m][kb+k] * B[n0+n][kb+k], both row-major, f32 accum.
// K-slot content XOR-swizzled by row (source-side pre-swizzle, rule #21).

__device__ __forceinline__ void stage_tiles_g(const short* __restrict__ A,
                                              const short* __restrict__ B,
                                              int m0, int n0, int k0,
                                              int lda, int ldb,
                                              short* As, short* Bs,
                                              int wave, int lane)
{
    #pragma unroll
    for (int t = 0; t < 2; ++t) {
        const int c  = (wave * 2 + t) * 64 + lane;   // 16B-chunk id 0..511
        const int r  = c >> 2;                        // tile row
        const int g  = c & 3;                         // LDS k-slot (8 bf16)
        const int sg = g ^ ((r >> 1) & 3);            // source pre-swizzle
        gload16(A + (size_t)(m0 + r) * lda + k0 + sg * 8, As + (wave * 2 + t) * 512);
        gload16(B + (size_t)(n0 + r) * ldb + k0 + sg * 8, Bs + (wave * 2 + t) * 512);
    }
}

template<int KSTEPS>
__device__ __forceinline__ void gemm_tile_g(const short* __restrict__ A,
                                            const short* __restrict__ B,
                                            int m0, int n0, int kbase,
                                            int lda, int ldb, int tid,
                                            short (*Sm)[2][4096],
                                            f32x4 acc[4][4])
{
    const int lane = tid & 63;
    const int wave = tid >> 6;
    const int rl   = lane & 15;
    const int g_rd = lane >> 4;
    const int wr   = wave >> 1;
    const int wc   = wave & 1;

    // prologue: two tiles in flight
    stage_tiles_g(A, B, m0, n0, kbase, lda, ldb, &Sm[0][0][0], &Sm[0][1][0], wave, lane);
    if (KSTEPS > 1)
        stage_tiles_g(A, B, m0, n0, kbase + BK, lda, ldb,
                      &Sm[1][0][0], &Sm[1][1][0], wave, lane);
    if (KSTEPS > 1) { VMCNT4; } else { VMCNT0; }
    SBAR;

    #pragma unroll
    for (int kt = 0; kt < KSTEPS; ++kt) {
        const int cur = kt % 3;
        if (kt + 2 < KSTEPS)
            stage_tiles_g(A, B, m0, n0, kbase + (kt + 2) * BK, lda, ldb,
                          &Sm[(kt + 2) % 3][0][0], &Sm[(kt + 2) % 3][1][0], wave, lane);

        bf16x8 af[4], bfr[4];
        #pragma unroll
        for (int mi = 0; mi < 4; ++mi) {
            const int r  = wr * 64 + mi * 16 + rl;
            const int sg = g_rd ^ ((r >> 1) & 3);     // read-side swizzle
            af[mi] = *reinterpret_cast<const bf16x8*>(&Sm[cur][0][r * BK + sg * 8]);
        }
        #pragma unroll
        for (int ni = 0; ni < 4; ++ni) {
            const int r  = wc * 64 + ni * 16 + rl;
            const int sg = g_rd ^ ((r >> 1) & 3);
            bfr[ni] = *reinterpret_cast<const bf16x8*>(&Sm[cur][1][r * BK + sg * 8]);
        }
        __builtin_amdgcn_s_setprio(1);
        #pragma unroll
        for (int mi = 0; mi < 4; ++mi)
            #pragma unroll
            for (int ni = 0; ni < 4; ++ni)
                acc[mi][ni] = __builtin_amdgcn_mfma_f32_16x16x32_bf16(
                    af[mi], bfr[ni], acc[mi][ni], 0, 0, 0);
        __builtin_amdgcn_s_setprio(0);

        if (kt + 1 < KSTEPS) {
            if (kt + 2 < KSTEPS) { VMCNT4; } else { VMCNT0; }
            SBAR;
        }
    }
}

// ---------------- Gram path ----------------

// partial G: Gp[z][c][c'] = sum_{n in chunk z} Bt[c][n] * Bt[c'][n]
template<int STEPS>
__global__ __launch_bounds__(256) void gemm_G(const short* __restrict__ Bt,
                                              float* __restrict__ Gp)
{
    __shared__ __align__(16) short Sm[3][2][4096];
    const int tid = threadIdx.x;
    const int m0 = blockIdx.y * BM, n0 = blockIdx.x * BN;
    const int z  = blockIdx.z;
    f32x4 acc[4][4] = {};
    gemm_tile_g<STEPS>(Bt, Bt, m0, n0, z * (STEPS * BK),
                       M_TOT, M_TOT, tid, Sm, acc);

    float* dst = Gp + (size_t)z * (C_TOT * C_TOT);
    const int lane = tid & 63, rl = lane & 15;
    const int wave = tid >> 6, wr = wave >> 1, wc = wave & 1;
    #pragma unroll
    for (int mi = 0; mi < 4; ++mi)
        #pragma unroll
        for (int i = 0; i < 4; ++i) {
            const int m = m0 + wr * 64 + mi * 16 + (lane >> 4) * 4 + i;
            #pragma unroll
            for (int ni = 0; ni < 4; ++ni)
                dst[m * C_TOT + n0 + wc * 64 + ni * 16 + rl] = acc[mi][ni][i];
        }
}

// Gb = bf16( sum_z Gp[z] )
__global__ __launch_bounds__(256) void g_reduce(const float* __restrict__ Gp,
                                                short* __restrict__ Gb,
                                                int nchunks)
{
    const int i4 = blockIdx.x * 256 + threadIdx.x;   // 16384 float4 groups
    float4 s = make_float4(0.f, 0.f, 0.f, 0.f);
    for (int z = 0; z < nchunks; ++z) {
        const float4 v = reinterpret_cast<const float4*>(
            Gp + (size_t)z * (C_TOT * C_TOT))[i4];
        s.x += v.x; s.y += v.y; s.z += v.z; s.w += v.w;
    }
    short4 o;
    o.x = f2bf(s.x); o.y = f2bf(s.y); o.z = f2bf(s.z); o.w = f2bf(s.w);
    reinterpret_cast<short4*>(Gb)[i4] = o;
}

// P[m] += sum_{c in Ci, c' in Cj} a[m,c] G[c,c'] a[m,c']   (quadrant-parallel)
// blockIdx.x: m-tile (50); blockIdx.y: quadrant (ci = y&1, cj = y>>1)
__global__ __launch_bounds__(256) void penalty_q(const short* __restrict__ Ab,
                                                 const short* __restrict__ Gb,
                                                 float* __restrict__ P)
{
    __shared__ __align__(16) short Sm[3][2][4096];
    const int tid = threadIdx.x;
    const int m0 = blockIdx.x * BM;
    const int ci = blockIdx.y & 1, cj = blockIdx.y >> 1;
    const int lane = tid & 63, rl = lane & 15;
    const int wave = tid >> 6, wr = wave >> 1, wc = wave & 1;

    f32x4 acc[4][4] = {};
    // dot[m,c'] = sum_{c in Ci} a[m,c] * G[cj*128 + c', c]   (G symmetric)
    gemm_tile_g<4>(Ab, Gb + (size_t)(cj * BM) * C_TOT, m0, 0, ci * BM,
                   C_TOT, C_TOT, tid, Sm, acc);

    #pragma unroll
    for (int mi = 0; mi < 4; ++mi)
        #pragma unroll
        for (int i = 0; i < 4; ++i) {
            const int m = m0 + wr * 64 + mi * 16 + (lane >> 4) * 4 + i;
            float s = 0.0f;
            #pragma unroll
            for (int ni = 0; ni < 4; ++ni) {
                const int cp = cj * BM + wc * 64 + ni * 16 + rl;
                s += acc[mi][ni][i] * bf2f(Ab[(size_t)m * C_TOT + cp]);
            }
            s += __shfl_xor(s, 1);
            s += __shfl_xor(s, 2);
            s += __shfl_xor(s, 4);
            s += __shfl_xor(s, 8);
            if (rl == 0) atomicAdd(&P[m], s);
        }
}

// ---------------- output GEMM (T1 bijective XCD-chunked swizzle) ----------------

__global__ __launch_bounds__(256) void gemm_out(const short* __restrict__ Ab,
                                                const short* __restrict__ Bb,
                                                const float* __restrict__ P,
                                                float* __restrict__ out)
{
    __shared__ __align__(16) short Sm[3][2][4096];   // 48 KB, reused by epilogue
    const int tid = threadIdx.x;
    const int lane = tid & 63, rl = lane & 15;
    const int wave = tid >> 6, wr = wave >> 1, wc = wave & 1;

    // bijective chunked XCD swizzle (m204): 2500 blocks, 8 XCDs
    const int nwg = NTILE * NTILE, q = nwg >> 3, r = nwg & 7;   // 312, 4
    const int orig = blockIdx.x;
    const int xcd = orig & 7, idx = orig >> 3;
    const int wg = (xcd < r ? xcd * (q + 1) : r * (q + 1) + (xcd - r) * q) + idx;
    const int m0 = (wg / NTILE) * BM;
    const int n0 = (wg % NTILE) * BN;

    f32x4 acc[4][4] = {};
    gemm_tile_g<8>(Ab, Bb, m0, n0, 0, C_TOT, C_TOT, tid, Sm, acc);

    float rs[4];
    #pragma unroll
    for (int ni = 0; ni < 4; ++ni)
        rs[ni] = rsqrtf(P[n0 + wc * 64 + ni * 16 + rl]);

    SBAR;   // all waves done with K-loop LDS before epilogue reuse

    // wave-private 16x68 f32 scratch (padded)
    float* Es = reinterpret_cast<float*>(Sm) + wave * 1088;
    #pragma unroll
    for (int mi = 0; mi < 4; ++mi) {
        #pragma unroll
        for (int ni = 0; ni < 4; ++ni)
            #pragma unroll
            for (int i = 0; i < 4; ++i)
                Es[((lane >> 4) * 4 + i) * 68 + ni * 16 + rl] = acc[mi][ni][i] * rs[ni];
        #pragma unroll
        for (int it = 0; it < 4; ++it) {
            const int f   = it * 64 + lane;
            const int row = f >> 4;
            const int c4  = f & 15;
            const float4 v = *reinterpret_cast<const float4*>(&Es[row * 68 + c4 * 4]);
            const int m = m0 + wr * 64 + mi * 16 + row;
            *reinterpret_cast<float4*>(&out[(size_t)m * M_TOT + n0 + wc * 64 + c4 * 4]) = v;
        }
    }
}

// ---------------- mid fallback: two-GEMM ----------------

__global__ __launch_bounds__(256) void gemm_penalty(const short* __restrict__ Ab,
                                                    const short* __restrict__ Bb,
                                                    float* __restrict__ P)
{
    __shared__ __align__(16) short Sm[3][2][4096];
    const int tid = threadIdx.x;
    const int m0 = blockIdx.y * BM, n0 = blockIdx.x * BN;
    f32x4 acc[4][4] = {};
    gemm_tile_g<8>(Ab, Bb, m0, n0, 0, C_TOT, C_TOT, tid, Sm, acc);

    const int lane = tid & 63, rl = lane & 15;
    const int wave = tid >> 6, wr = wave >> 1;
    #pragma unroll
    for (int mi = 0; mi < 4; ++mi) {
        #pragma unroll
        for (int i = 0; i < 4; ++i) {
            const int m = m0 + wr * 64 + mi * 16 + (lane >> 4) * 4 + i;
            float s = 0.0f;
            #pragma unroll
            for (int ni = 0; ni < 4; ++ni) {
                const float v = acc[mi][ni][i];
                s += v * v;
            }
            s += __shfl_xor(s, 1);
            s += __shfl_xor(s, 2);
            s += __shfl_xor(s, 4);
            s += __shfl_xor(s, 8);
            if (rl == 0) atomicAdd(&P[m], s);
        }
    }
}

__global__ __launch_bounds__(256) void gemm_out_plain(const short* __restrict__ Ab,
                                                      const short* __restrict__ Bb,
                                                      const float* __restrict__ P,
                                                      float* __restrict__ out)
{
    __shared__ __align__(16) short Sm[3][2][4096];
    const int tid = threadIdx.x;
    const int lane = tid & 63, rl = lane & 15;
    const int wave = tid >> 6, wr = wave >> 1, wc = wave & 1;
    const int m0 = blockIdx.y * BM, n0 = blockIdx.x * BN;

    f32x4 acc[4][4] = {};
    gemm_tile_g<8>(Ab, Bb, m0, n0, 0, C_TOT, C_TOT, tid, Sm, acc);

    float rs[4];
    #pragma unroll
    for (int ni = 0; ni < 4; ++ni)
        rs[ni] = rsqrtf(P[n0 + wc * 64 + ni * 16 + rl]);

    SBAR;

    float* Es = reinterpret_cast<float*>(Sm) + wave * 1088;
    #pragma unroll
    for (int mi = 0; mi < 4; ++mi) {
        #pragma unroll
        for (int ni = 0; ni < 4; ++ni)
            #pragma unroll
            for (int i = 0; i < 4; ++i)
                Es[((lane >> 4) * 4 + i) * 68 + ni * 16 + rl] = acc[mi][ni][i] * rs[ni];
        #pragma unroll
        for (int it = 0; it < 4; ++it) {
            const int f   = it * 64 + lane;
            const int row = f >> 4;
            const int c4  = f & 15;
            const float4 v = *reinterpret_cast<const float4*>(&Es[row * 68 + c4 * 4]);
            const int m = m0 + wr * 64 + mi * 16 + row;
            *reinterpret_cast<float4*>(&out[(size_t)m * M_TOT + n0 + wc * 64 + c4 * 4]) = v;
        }
    }
}

// ---------------- final fallback (round-1) ----------------

__global__ __launch_bounds__(256) void corr_gemm(const float* __restrict__ A,
                                                 const float* __restrict__ Bm,
                                                 float* __restrict__ out,
                                                 float* __restrict__ penalty)
{
    __shared__ short As[BM * BK];
    __shared__ short Bs[BN * BK];

    const int tid  = threadIdx.x;
    const int lane = tid & 63;
    const int wave = tid >> 6;
    const int wr   = wave >> 1;
    const int wc   = wave & 1;
    const int m0   = blockIdx.y * BM;
    const int n0   = blockIdx.x * BN;
    const int g_rd = lane >> 4;
    const int rl   = lane & 15;

    f32x4 acc[4][4] = {};

    for (int k0 = 0; k0 < C_TOT; k0 += BK) {
        #pragma unroll
        for (int half = 0; half < 2; ++half) {
            const int cc = tid + half * 256;
            const int r  = cc >> 2;
            const int g  = cc & 3;
            const int sg = g ^ ((r >> 1) & 3);

            const float4* pa = reinterpret_cast<const float4*>(
                A + (size_t)(m0 + r) * C_TOT + k0 + g * 8);
            float4 a0 = pa[0], a1 = pa[1];
            bf16x8 wa;
            wa[0]=f2bf(a0.x); wa[1]=f2bf(a0.y); wa[2]=f2bf(a0.z); wa[3]=f2bf(a0.w);
            wa[4]=f2bf(a1.x); wa[5]=f2bf(a1.y); wa[6]=f2bf(a1.z); wa[7]=f2bf(a1.w);
            *reinterpret_cast<bf16x8*>(&As[r * BK + sg * 8]) = wa;

            const float4* pb = reinterpret_cast<const float4*>(
                Bm + (size_t)(n0 + r) * C_TOT + k0 + g * 8);
            float4 b0 = pb[0], b1 = pb[1];
            bf16x8 wb;
            wb[0]=f2bf(b0.x); wb[1]=f2bf(b0.y); wb[2]=f2bf(b0.z); wb[3]=f2bf(b0.w);
            wb[4]=f2bf(b1.x); wb[5]=f2bf(b1.y); wb[6]=f2bf(b1.z); wb[7]=f2bf(b1.w);
            *reinterpret_cast<bf16x8*>(&Bs[r * BK + sg * 8]) = wb;
        }
        __syncthreads();

        bf16x8 af[4], bfr[4];
        #pragma unroll
        for (int mi = 0; mi < 4; ++mi) {
            const int r  = wr * 64 + mi * 16 + rl;
            const int sg = g_rd ^ ((r >> 1) & 3);
            af[mi] = *reinterpret_cast<const bf16x8*>(&As[r * BK + sg * 8]);
        }
        #pragma unroll
        for (int ni = 0; ni < 4; ++ni) {
            const int r  = wc * 64 + ni * 16 + rl;
            const int sg = g_rd ^ ((r >> 1) & 3);
            bfr[ni] = *reinterpret_cast<const bf16x8*>(&Bs[r * BK + sg * 8]);
        }
        #pragma unroll
        for (int mi = 0; mi < 4; ++mi)
            #pragma unroll
            for (int ni = 0; ni < 4; ++ni)
                acc[mi][ni] = __builtin_amdgcn_mfma_f32_16x16x32_bf16(
                    af[mi], bfr[ni], acc[mi][ni], 0, 0, 0);
        __syncthreads();
    }

    const float inv_c = 1.0f / (float)C_TOT;
    #pragma unroll
    for (int mi = 0; mi < 4; ++mi) {
        #pragma unroll
        for (int i = 0; i < 4; ++i) {
            const int m = m0 + wr * 64 + mi * 16 + (lane >> 4) * 4 + i;
            float s = 0.0f;
            #pragma unroll
            for (int ni = 0; ni < 4; ++ni) {
                const float v = acc[mi][ni][i] * inv_c;
                out[(size_t)m * M_TOT + n0 + wc * 64 + ni * 16 + rl] = v;
                s += v * v;
            }
            s += __shfl_xor(s, 1);
            s += __shfl_xor(s, 2);
            s += __shfl_xor(s, 4);
            s += __shfl_xor(s, 8);
            if (rl == 0) atomicAdd(&penalty[m], s);
        }
    }
}

__global__ __launch_bounds__(256) void scale_k(float* __restrict__ out,
                                               const float* __restrict__ penalty)
{
    const unsigned cols4 = M_TOT / 4;
    const unsigned total = (unsigned)M_TOT * cols4;
    float4* o4 = reinterpret_cast<float4*>(out);
    const float4* p4 = reinterpret_cast<const float4*>(penalty);
    for (unsigned idx = blockIdx.x * blockDim.x + threadIdx.x; idx < total;
         idx += gridDim.x * blockDim.x) {
        const unsigned n4 = idx % cols4;
        const float4 p = p4[n4];
        float4 v = o4[idx];
        v.x *= rsqrtf(p.x);
        v.y *= rsqrtf(p.y);
        v.z *= rsqrtf(p.z);
        v.w *= rsqrtf(p.w);
        o4[idx] = v;
    }
}

// ---------------- launch ----------------

extern "C" void kernel_launch(void* const* d_in, const int* in_sizes, int n_in,
                              void* d_out, int out_size, void* d_ws, size_t ws_size,
                              hipStream_t stream) {
    const float* A = (const float*)d_in[0];
    const float* B = (const float*)d_in[1];
    float* out     = (float*)d_out;

    const size_t mat_sh = (size_t)M_TOT * C_TOT;                   // 1,638,400
    const size_t sz_ab  = mat_sh * sizeof(short);                  // 3,276,800
    const size_t sz_gb  = (size_t)C_TOT * C_TOT * sizeof(short);   // 131,072
    const size_t sz_p   = (size_t)M_TOT * sizeof(float);           // 25,600
    const size_t sz_gq  = (size_t)C_TOT * C_TOT * sizeof(float);   // 262,144
    const size_t base_need = 3 * sz_ab + sz_gb + sz_p;
    const size_t need_f40  = base_need + 40 * sz_gq;   // ~20.5 MB
    const size_t need_f20  = base_need + 20 * sz_gq;   // ~15.3 MB
    const size_t need_mid  = 2 * sz_ab + sz_p;         // ~6.6 MB

    dim3 grid2(NTILE, NTILE);   // 50 x 50

    if (ws_size >= need_f20) {
        short* Ab = (short*)d_ws;
        short* Bb = Ab + mat_sh;
        short* Bt = Bb + mat_sh;
        short* Gb = Bt + mat_sh;
        float* P  = (float*)((char*)d_ws + 3 * sz_ab + sz_gb);
        float* Gp = (float*)((char*)d_ws + 3 * sz_ab + sz_gb + sz_p);

        prep<<<500, 256, 0, stream>>>(A, B, Ab, Bb, Bt, P);
        if (ws_size >= need_f40) {
            gemm_G<5><<<dim3(2, 2, 40), 256, 0, stream>>>(Bt, Gp);   // chunk = 160
            g_reduce<<<64, 256, 0, stream>>>(Gp, Gb, 40);
        } else {
            gemm_G<10><<<dim3(2, 2, 20), 256, 0, stream>>>(Bt, Gp);  // chunk = 320
            g_reduce<<<64, 256, 0, stream>>>(Gp, Gb, 20);
        }
        penalty_q<<<dim3(NTILE, 4), 256, 0, stream>>>(Ab, Gb, P);
        gemm_out<<<NTILE * NTILE, 256, 0, stream>>>(Ab, Bb, P, out);
    } else if (ws_size >= need_mid) {
        short* Ab = (short*)d_ws;
        short* Bb = Ab + mat_sh;
        float* P  = (float*)(Bb + mat_sh);

        hipMemsetAsync(P, 0, sz_p, stream);
        convert_ab<<<1600, 256, 0, stream>>>(A, B, Ab, Bb);
        gemm_penalty<<<grid2, dim3(256), 0, stream>>>(Ab, Bb, P);
        gemm_out_plain<<<grid2, dim3(256), 0, stream>>>(Ab, Bb, P, out);
    } else {
        float* penalty = (float*)d_ws;
        hipMemsetAsync(penalty, 0, sz_p, stream);
        corr_gemm<<<grid2, dim3(256), 0, stream>>>(A, B, out, penalty);
        scale_k<<<2048, 256, 0, stream>>>(out, penalty);
    }
}

// Round 8
// 84.011 us; speedup vs baseline: 1.6477x; 1.0119x over previous
//
#include <hip/hip_runtime.h>

typedef __attribute__((ext_vector_type(8))) short bf16x8;
typedef __attribute__((ext_vector_type(4))) float f32x4;

#define M_TOT 6400   // 80*80 flattened spatial positions
#define C_TOT 256    // channels (K of the main GEMM)
#define BM 128
#define BN 128
#define BK 32
#define NTILE 50     // 6400 / 128
#define ONM 50       // gemm_out m-tiles (128)
#define ONN 25       // gemm_out n-tiles (256)

#define VMCNT0 asm volatile("s_waitcnt vmcnt(0)" ::: "memory")
#define VMCNT4 asm volatile("s_waitcnt vmcnt(4)" ::: "memory")
#define VMCNT6 asm volatile("s_waitcnt vmcnt(6)" ::: "memory")
#define SBAR   __builtin_amdgcn_s_barrier()

// f32 -> bf16 round-to-nearest-even
__device__ __forceinline__ short f2bf(float f) {
    unsigned u = __float_as_uint(f);
    u = (u + 0x7fffu + ((u >> 16) & 1u)) >> 16;
    return (short)u;
}
__device__ __forceinline__ float bf2f(short s) {
    return __uint_as_float(((unsigned)(unsigned short)s) << 16);
}

// async global->LDS, 16B per lane; LDS dst is wave-uniform base + lane*16
__device__ __forceinline__ void gload16(const short* g, short* l) {
    __builtin_amdgcn_global_load_lds(
        (const __attribute__((address_space(1))) void*)g,
        (__attribute__((address_space(3))) void*)l, 16, 0, 0);
}

// ---------------- fused prep: A->Ab, B->(Bb,Bt), zero P ----------------

__global__ __launch_bounds__(256) void prep(const float* __restrict__ A,
                                            const float* __restrict__ Bm,
                                            short* __restrict__ Ab,
                                            short* __restrict__ Bb,
                                            short* __restrict__ Bt,
                                            float* __restrict__ P)
{
    __shared__ __align__(16) short Lb[64][72];
    const int bid = blockIdx.x;
    const int t   = threadIdx.x;

    if (bid < 400) {
        const int n0 = (bid % 100) * 64;
        const int c0 = (bid / 100) * 64;
        const int r  = t >> 2;
        const int cb = (t & 3) * 16;

        const float4* src = reinterpret_cast<const float4*>(
            Bm + (size_t)(n0 + r) * C_TOT + c0 + cb);
        const float4 v0 = src[0], v1 = src[1], v2 = src[2], v3 = src[3];
        bf16x8 w0, w1;
        w0[0]=f2bf(v0.x); w0[1]=f2bf(v0.y); w0[2]=f2bf(v0.z); w0[3]=f2bf(v0.w);
        w0[4]=f2bf(v1.x); w0[5]=f2bf(v1.y); w0[6]=f2bf(v1.z); w0[7]=f2bf(v1.w);
        w1[0]=f2bf(v2.x); w1[1]=f2bf(v2.y); w1[2]=f2bf(v2.z); w1[3]=f2bf(v2.w);
        w1[4]=f2bf(v3.x); w1[5]=f2bf(v3.y); w1[6]=f2bf(v3.z); w1[7]=f2bf(v3.w);
        *reinterpret_cast<bf16x8*>(&Lb[r][cb])     = w0;
        *reinterpret_cast<bf16x8*>(&Lb[r][cb + 8]) = w1;
        short* brow = Bb + (size_t)(n0 + r) * C_TOT + c0 + cb;
        *reinterpret_cast<bf16x8*>(brow)     = w0;
        *reinterpret_cast<bf16x8*>(brow + 8) = w1;
        __syncthreads();

        #pragma unroll
        for (int p = 0; p < 2; ++p) {
            const int q = t + p * 256;
            const int c = q >> 3;
            const int h = q & 7;
            bf16x8 w;
            #pragma unroll
            for (int j = 0; j < 8; ++j) w[j] = Lb[h * 8 + j][c];
            *reinterpret_cast<bf16x8*>(&Bt[(size_t)(c0 + c) * M_TOT + n0 + h * 8]) = w;
        }
    } else {
        const int aid = bid - 400;   // 0..99
        if (aid == 0)
            for (int j = t; j < M_TOT; j += 256) P[j] = 0.0f;
        const int base = aid * 2048;
        #pragma unroll
        for (int it = 0; it < 8; ++it) {
            const int i = base + it * 256 + t;
            const float4 v0 = reinterpret_cast<const float4*>(A + (size_t)i * 8)[0];
            const float4 v1 = reinterpret_cast<const float4*>(A + (size_t)i * 8)[1];
            bf16x8 w;
            w[0]=f2bf(v0.x); w[1]=f2bf(v0.y); w[2]=f2bf(v0.z); w[3]=f2bf(v0.w);
            w[4]=f2bf(v1.x); w[5]=f2bf(v1.y); w[6]=f2bf(v1.z); w[7]=f2bf(v1.w);
            *reinterpret_cast<bf16x8*>(Ab + (size_t)i * 8) = w;
        }
    }
}

// A and B (mid fallback path)
__global__ __launch_bounds__(256) void convert_ab(const float* __restrict__ A,
                                                  const float* __restrict__ Bm,
                                                  short* __restrict__ Ab,
                                                  short* __restrict__ Bb)
{
    const int n8 = M_TOT * C_TOT / 8;
    for (int i = blockIdx.x * blockDim.x + threadIdx.x; i < 2 * n8;
         i += gridDim.x * blockDim.x) {
        const float* s = (i < n8) ? (A + (size_t)i * 8) : (Bm + (size_t)(i - n8) * 8);
        short* d       = (i < n8) ? (Ab + (size_t)i * 8) : (Bb + (size_t)(i - n8) * 8);
        const float4 v0 = reinterpret_cast<const float4*>(s)[0];
        const float4 v1 = reinterpret_cast<const float4*>(s)[1];
        bf16x8 w;
        w[0]=f2bf(v0.x); w[1]=f2bf(v0.y); w[2]=f2bf(v0.z); w[3]=f2bf(v0.w);
        w[4]=f2bf(v1.x); w[5]=f2bf(v1.y); w[6]=f2bf(v1.z); w[7]=f2bf(v1.w);
        *reinterpret_cast<bf16x8*>(d) = w;
    }
}

// ------- 128x128 tile machinery (Gram / penalty / fallbacks) -------

__device__ __forceinline__ void stage_tiles_g(const short* __restrict__ A,
                                              const short* __restrict__ B,
                                              int m0, int n0, int k0,
                                              int lda, int ldb,
                                              short* As, short* Bs,
                                              int wave, int lane)
{
    #pragma unroll
    for (int t = 0; t < 2; ++t) {
        const int c  = (wave * 2 + t) * 64 + lane;
        const int r  = c >> 2;
        const int g  = c & 3;
        const int sg = g ^ ((r >> 1) & 3);
        gload16(A + (size_t)(m0 + r) * lda + k0 + sg * 8, As + (wave * 2 + t) * 512);
        gload16(B + (size_t)(n0 + r) * ldb + k0 + sg * 8, Bs + (wave * 2 + t) * 512);
    }
}

template<int KSTEPS>
__device__ __forceinline__ void gemm_tile_g(const short* __restrict__ A,
                                            const short* __restrict__ B,
                                            int m0, int n0, int kbase,
                                            int lda, int ldb, int tid,
                                            short (*Sm)[2][4096],
                                            f32x4 acc[4][4])
{
    const int lane = tid & 63;
    const int wave = tid >> 6;
    const int rl   = lane & 15;
    const int g_rd = lane >> 4;
    const int wr   = wave >> 1;
    const int wc   = wave & 1;

    stage_tiles_g(A, B, m0, n0, kbase, lda, ldb, &Sm[0][0][0], &Sm[0][1][0], wave, lane);
    if (KSTEPS > 1)
        stage_tiles_g(A, B, m0, n0, kbase + BK, lda, ldb,
                      &Sm[1][0][0], &Sm[1][1][0], wave, lane);
    if (KSTEPS > 1) { VMCNT4; } else { VMCNT0; }
    SBAR;

    #pragma unroll
    for (int kt = 0; kt < KSTEPS; ++kt) {
        const int cur = kt % 3;
        if (kt + 2 < KSTEPS)
            stage_tiles_g(A, B, m0, n0, kbase + (kt + 2) * BK, lda, ldb,
                          &Sm[(kt + 2) % 3][0][0], &Sm[(kt + 2) % 3][1][0], wave, lane);

        bf16x8 af[4], bfr[4];
        #pragma unroll
        for (int mi = 0; mi < 4; ++mi) {
            const int r  = wr * 64 + mi * 16 + rl;
            const int sg = g_rd ^ ((r >> 1) & 3);
            af[mi] = *reinterpret_cast<const bf16x8*>(&Sm[cur][0][r * BK + sg * 8]);
        }
        #pragma unroll
        for (int ni = 0; ni < 4; ++ni) {
            const int r  = wc * 64 + ni * 16 + rl;
            const int sg = g_rd ^ ((r >> 1) & 3);
            bfr[ni] = *reinterpret_cast<const bf16x8*>(&Sm[cur][1][r * BK + sg * 8]);
        }
        __builtin_amdgcn_s_setprio(1);
        #pragma unroll
        for (int mi = 0; mi < 4; ++mi)
            #pragma unroll
            for (int ni = 0; ni < 4; ++ni)
                acc[mi][ni] = __builtin_amdgcn_mfma_f32_16x16x32_bf16(
                    af[mi], bfr[ni], acc[mi][ni], 0, 0, 0);
        __builtin_amdgcn_s_setprio(0);

        if (kt + 1 < KSTEPS) {
            if (kt + 2 < KSTEPS) { VMCNT4; } else { VMCNT0; }
            SBAR;
        }
    }
}

// ---------------- Gram path ----------------

template<int STEPS>
__global__ __launch_bounds__(256) void gemm_G(const short* __restrict__ Bt,
                                              float* __restrict__ Gp)
{
    __shared__ __align__(16) short Sm[3][2][4096];
    const int tid = threadIdx.x;
    const int m0 = blockIdx.y * BM, n0 = blockIdx.x * BN;
    const int z  = blockIdx.z;
    f32x4 acc[4][4] = {};
    gemm_tile_g<STEPS>(Bt, Bt, m0, n0, z * (STEPS * BK),
                       M_TOT, M_TOT, tid, Sm, acc);

    float* dst = Gp + (size_t)z * (C_TOT * C_TOT);
    const int lane = tid & 63, rl = lane & 15;
    const int wave = tid >> 6, wr = wave >> 1, wc = wave & 1;
    #pragma unroll
    for (int mi = 0; mi < 4; ++mi)
        #pragma unroll
        for (int i = 0; i < 4; ++i) {
            const int m = m0 + wr * 64 + mi * 16 + (lane >> 4) * 4 + i;
            #pragma unroll
            for (int ni = 0; ni < 4; ++ni)
                dst[m * C_TOT + n0 + wc * 64 + ni * 16 + rl] = acc[mi][ni][i];
        }
}

__global__ __launch_bounds__(256) void g_reduce(const float* __restrict__ Gp,
                                                short* __restrict__ Gb,
                                                int nchunks)
{
    const int i4 = blockIdx.x * 256 + threadIdx.x;
    float4 s = make_float4(0.f, 0.f, 0.f, 0.f);
    for (int z = 0; z < nchunks; ++z) {
        const float4 v = reinterpret_cast<const float4*>(
            Gp + (size_t)z * (C_TOT * C_TOT))[i4];
        s.x += v.x; s.y += v.y; s.z += v.z; s.w += v.w;
    }
    short4 o;
    o.x = f2bf(s.x); o.y = f2bf(s.y); o.z = f2bf(s.z); o.w = f2bf(s.w);
    reinterpret_cast<short4*>(Gb)[i4] = o;
}

__global__ __launch_bounds__(256) void penalty_q(const short* __restrict__ Ab,
                                                 const short* __restrict__ Gb,
                                                 float* __restrict__ P)
{
    __shared__ __align__(16) short Sm[3][2][4096];
    const int tid = threadIdx.x;
    const int m0 = blockIdx.x * BM;
    const int ci = blockIdx.y & 1, cj = blockIdx.y >> 1;
    const int lane = tid & 63, rl = lane & 15;
    const int wave = tid >> 6, wr = wave >> 1, wc = wave & 1;

    f32x4 acc[4][4] = {};
    gemm_tile_g<4>(Ab, Gb + (size_t)(cj * BM) * C_TOT, m0, 0, ci * BM,
                   C_TOT, C_TOT, tid, Sm, acc);

    #pragma unroll
    for (int mi = 0; mi < 4; ++mi)
        #pragma unroll
        for (int i = 0; i < 4; ++i) {
            const int m = m0 + wr * 64 + mi * 16 + (lane >> 4) * 4 + i;
            float s = 0.0f;
            #pragma unroll
            for (int ni = 0; ni < 4; ++ni) {
                const int cp = cj * BM + wc * 64 + ni * 16 + rl;
                s += acc[mi][ni][i] * bf2f(Ab[(size_t)m * C_TOT + cp]);
            }
            s += __shfl_xor(s, 1);
            s += __shfl_xor(s, 2);
            s += __shfl_xor(s, 4);
            s += __shfl_xor(s, 8);
            if (rl == 0) atomicAdd(&P[m], s);
        }
}

// ---------------- output GEMM: 128x256 tile, 4 waves x (64x128) ----------------
// Sm buffer: [A 128x32 | B 256x32] = 12288 shorts (24 KB), x3 buffers = 72 KB.
// Stage = 6 gload16/thread (2 for A, 4 for B) -> counted wait vmcnt(6).

#define OBUF 12288
#define OB_B 4096     // B region offset within a buffer (shorts)

__device__ __forceinline__ void stage_tiles_o(const short* __restrict__ A,
                                              const short* __restrict__ B,
                                              int m0, int n0, int k0,
                                              short* buf, int wave, int lane)
{
    #pragma unroll
    for (int t = 0; t < 2; ++t) {
        const int c  = (wave * 2 + t) * 64 + lane;   // 0..511 (A: 128 rows)
        const int r  = c >> 2;
        const int g  = c & 3;
        const int sg = g ^ ((r >> 1) & 3);
        gload16(A + (size_t)(m0 + r) * C_TOT + k0 + sg * 8, buf + (wave * 2 + t) * 512);
    }
    #pragma unroll
    for (int t = 0; t < 4; ++t) {
        const int c  = (wave * 4 + t) * 64 + lane;   // 0..1023 (B: 256 rows)
        const int r  = c >> 2;
        const int g  = c & 3;
        const int sg = g ^ ((r >> 1) & 3);
        gload16(B + (size_t)(n0 + r) * C_TOT + k0 + sg * 8,
                buf + OB_B + (wave * 4 + t) * 512);
    }
}

__global__ __launch_bounds__(256, 2) void gemm_out(const short* __restrict__ Ab,
                                                   const short* __restrict__ Bb,
                                                   const float* __restrict__ P,
                                                   float* __restrict__ out)
{
    __shared__ __align__(16) short Sm[3][OBUF];   // 72 KB
    const int tid = threadIdx.x;
    const int lane = tid & 63, rl = lane & 15;
    const int g_rd = lane >> 4;
    const int wave = tid >> 6, wr = wave >> 1, wc = wave & 1;

    // bijective chunked XCD swizzle: 1250 blocks, 8 XCDs (q=156, r=2)
    const int nwg = ONM * ONN, q = nwg >> 3, r = nwg & 7;
    const int orig = blockIdx.x;
    const int xcd = orig & 7, idx = orig >> 3;
    const int wg = (xcd < r ? xcd * (q + 1) : r * (q + 1) + (xcd - r) * q) + idx;
    const int m0 = (wg / ONN) * 128;
    const int n0 = (wg % ONN) * 256;

    f32x4 acc[4][8] = {};

    // prologue: two K-tiles in flight
    stage_tiles_o(Ab, Bb, m0, n0, 0,  &Sm[0][0], wave, lane);
    stage_tiles_o(Ab, Bb, m0, n0, BK, &Sm[1][0], wave, lane);
    VMCNT6; SBAR;

    #pragma unroll
    for (int kt = 0; kt < 8; ++kt) {
        const int cur = kt % 3;
        if (kt + 2 < 8)
            stage_tiles_o(Ab, Bb, m0, n0, (kt + 2) * BK, &Sm[(kt + 2) % 3][0], wave, lane);

        bf16x8 af[4], bfr[8];
        #pragma unroll
        for (int mi = 0; mi < 4; ++mi) {
            const int rr = wr * 64 + mi * 16 + rl;
            const int sg = g_rd ^ ((rr >> 1) & 3);
            af[mi] = *reinterpret_cast<const bf16x8*>(&Sm[cur][rr * BK + sg * 8]);
        }
        #pragma unroll
        for (int ni = 0; ni < 8; ++ni) {
            const int rr = wc * 128 + ni * 16 + rl;
            const int sg = g_rd ^ ((rr >> 1) & 3);
            bfr[ni] = *reinterpret_cast<const bf16x8*>(&Sm[cur][OB_B + rr * BK + sg * 8]);
        }
        __builtin_amdgcn_s_setprio(1);
        #pragma unroll
        for (int mi = 0; mi < 4; ++mi)
            #pragma unroll
            for (int ni = 0; ni < 8; ++ni)
                acc[mi][ni] = __builtin_amdgcn_mfma_f32_16x16x32_bf16(
                    af[mi], bfr[ni], acc[mi][ni], 0, 0, 0);
        __builtin_amdgcn_s_setprio(0);

        if (kt + 1 < 8) {
            if (kt + 2 < 8) { VMCNT6; } else { VMCNT0; }
            SBAR;
        }
    }

    float rs[8];
    #pragma unroll
    for (int ni = 0; ni < 8; ++ni)
        rs[ni] = rsqrtf(P[n0 + wc * 128 + ni * 16 + rl]);

    SBAR;   // all waves done reading Sm before epilogue scratch reuse

    // wave-private 16x132 f32 scratch (2112 floats = 8448 B per wave)
    float* Es = reinterpret_cast<float*>(Sm) + wave * 2112;
    #pragma unroll
    for (int mi = 0; mi < 4; ++mi) {
        #pragma unroll
        for (int ni = 0; ni < 8; ++ni)
            #pragma unroll
            for (int i = 0; i < 4; ++i)
                Es[((lane >> 4) * 4 + i) * 132 + ni * 16 + rl] = acc[mi][ni][i] * rs[ni];
        #pragma unroll
        for (int it = 0; it < 8; ++it) {
            const int f   = it * 64 + lane;   // 0..511
            const int row = f >> 5;           // 0..15
            const int c4  = f & 31;           // float4 column 0..31
            const float4 v = *reinterpret_cast<const float4*>(&Es[row * 132 + c4 * 4]);
            const int m = m0 + wr * 64 + mi * 16 + row;
            *reinterpret_cast<float4*>(
                &out[(size_t)m * M_TOT + n0 + wc * 128 + c4 * 4]) = v;
        }
    }
}

// ---------------- mid fallback: two-GEMM (128^2) ----------------

__global__ __launch_bounds__(256) void gemm_penalty(const short* __restrict__ Ab,
                                                    const short* __restrict__ Bb,
                                                    float* __restrict__ P)
{
    __shared__ __align__(16) short Sm[3][2][4096];
    const int tid = threadIdx.x;
    const int m0 = blockIdx.y * BM, n0 = blockIdx.x * BN;
    f32x4 acc[4][4] = {};
    gemm_tile_g<8>(Ab, Bb, m0, n0, 0, C_TOT, C_TOT, tid, Sm, acc);

    const int lane = tid & 63, rl = lane & 15;
    const int wave = tid >> 6, wr = wave >> 1;
    #pragma unroll
    for (int mi = 0; mi < 4; ++mi) {
        #pragma unroll
        for (int i = 0; i < 4; ++i) {
            const int m = m0 + wr * 64 + mi * 16 + (lane >> 4) * 4 + i;
            float s = 0.0f;
            #pragma unroll
            for (int ni = 0; ni < 4; ++ni) {
                const float v = acc[mi][ni][i];
                s += v * v;
            }
            s += __shfl_xor(s, 1);
            s += __shfl_xor(s, 2);
            s += __shfl_xor(s, 4);
            s += __shfl_xor(s, 8);
            if (rl == 0) atomicAdd(&P[m], s);
        }
    }
}

__global__ __launch_bounds__(256) void gemm_out_plain(const short* __restrict__ Ab,
                                                      const short* __restrict__ Bb,
                                                      const float* __restrict__ P,
                                                      float* __restrict__ out)
{
    __shared__ __align__(16) short Sm[3][2][4096];
    const int tid = threadIdx.x;
    const int lane = tid & 63, rl = lane & 15;
    const int wave = tid >> 6, wr = wave >> 1, wc = wave & 1;
    const int m0 = blockIdx.y * BM, n0 = blockIdx.x * BN;

    f32x4 acc[4][4] = {};
    gemm_tile_g<8>(Ab, Bb, m0, n0, 0, C_TOT, C_TOT, tid, Sm, acc);

    float rs[4];
    #pragma unroll
    for (int ni = 0; ni < 4; ++ni)
        rs[ni] = rsqrtf(P[n0 + wc * 64 + ni * 16 + rl]);

    SBAR;

    float* Es = reinterpret_cast<float*>(Sm) + wave * 1088;
    #pragma unroll
    for (int mi = 0; mi < 4; ++mi) {
        #pragma unroll
        for (int ni = 0; ni < 4; ++ni)
            #pragma unroll
            for (int i = 0; i < 4; ++i)
                Es[((lane >> 4) * 4 + i) * 68 + ni * 16 + rl] = acc[mi][ni][i] * rs[ni];
        #pragma unroll
        for (int it = 0; it < 4; ++it) {
            const int f   = it * 64 + lane;
            const int row = f >> 4;
            const int c4  = f & 15;
            const float4 v = *reinterpret_cast<const float4*>(&Es[row * 68 + c4 * 4]);
            const int m = m0 + wr * 64 + mi * 16 + row;
            *reinterpret_cast<float4*>(&out[(size_t)m * M_TOT + n0 + wc * 64 + c4 * 4]) = v;
        }
    }
}

// ---------------- final fallback (round-1) ----------------

__global__ __launch_bounds__(256) void corr_gemm(const float* __restrict__ A,
                                                 const float* __restrict__ Bm,
                                                 float* __restrict__ out,
                                                 float* __restrict__ penalty)
{
    __shared__ short As[BM * BK];
    __shared__ short Bs[BN * BK];

    const int tid  = threadIdx.x;
    const int lane = tid & 63;
    const int wave = tid >> 6;
    const int wr   = wave >> 1;
    const int wc   = wave & 1;
    const int m0   = blockIdx.y * BM;
    const int n0   = blockIdx.x * BN;
    const int g_rd = lane >> 4;
    const int rl   = lane & 15;

    f32x4 acc[4][4] = {};

    for (int k0 = 0; k0 < C_TOT; k0 += BK) {
        #pragma unroll
        for (int half = 0; half < 2; ++half) {
            const int cc = tid + half * 256;
            const int r  = cc >> 2;
            const int g  = cc & 3;
            const int sg = g ^ ((r >> 1) & 3);

            const float4* pa = reinterpret_cast<const float4*>(
                A + (size_t)(m0 + r) * C_TOT + k0 + g * 8);
            float4 a0 = pa[0], a1 = pa[1];
            bf16x8 wa;
            wa[0]=f2bf(a0.x); wa[1]=f2bf(a0.y); wa[2]=f2bf(a0.z); wa[3]=f2bf(a0.w);
            wa[4]=f2bf(a1.x); wa[5]=f2bf(a1.y); wa[6]=f2bf(a1.z); wa[7]=f2bf(a1.w);
            *reinterpret_cast<bf16x8*>(&As[r * BK + sg * 8]) = wa;

            const float4* pb = reinterpret_cast<const float4*>(
                Bm + (size_t)(n0 + r) * C_TOT + k0 + g * 8);
            float4 b0 = pb[0], b1 = pb[1];
            bf16x8 wb;
            wb[0]=f2bf(b0.x); wb[1]=f2bf(b0.y); wb[2]=f2bf(b0.z); wb[3]=f2bf(b0.w);
            wb[4]=f2bf(b1.x); wb[5]=f2bf(b1.y); wb[6]=f2bf(b1.z); wb[7]=f2bf(b1.w);
            *reinterpret_cast<bf16x8*>(&Bs[r * BK + sg * 8]) = wb;
        }
        __syncthreads();

        bf16x8 af[4], bfr[4];
        #pragma unroll
        for (int mi = 0; mi < 4; ++mi) {
            const int r  = wr * 64 + mi * 16 + rl;
            const int sg = g_rd ^ ((r >> 1) & 3);
            af[mi] = *reinterpret_cast<const bf16x8*>(&As[r * BK + sg * 8]);
        }
        #pragma unroll
        for (int ni = 0; ni < 4; ++ni) {
            const int r  = wc * 64 + ni * 16 + rl;
            const int sg = g_rd ^ ((r >> 1) & 3);
            bfr[ni] = *reinterpret_cast<const bf16x8*>(&Bs[r * BK + sg * 8]);
        }
        #pragma unroll
        for (int mi = 0; mi < 4; ++mi)
            #pragma unroll
            for (int ni = 0; ni < 4; ++ni)
                acc[mi][ni] = __builtin_amdgcn_mfma_f32_16x16x32_bf16(
                    af[mi], bfr[ni], acc[mi][ni], 0, 0, 0);
        __syncthreads();
    }

    const float inv_c = 1.0f / (float)C_TOT;
    #pragma unroll
    for (int mi = 0; mi < 4; ++mi) {
        #pragma unroll
        for (int i = 0; i < 4; ++i) {
            const int m = m0 + wr * 64 + mi * 16 + (lane >> 4) * 4 + i;
            float s = 0.0f;
            #pragma unroll
            for (int ni = 0; ni < 4; ++ni) {
                const float v = acc[mi][ni][i] * inv_c;
                out[(size_t)m * M_TOT + n0 + wc * 64 + ni * 16 + rl] = v;
                s += v * v;
            }
            s += __shfl_xor(s, 1);
            s += __shfl_xor(s, 2);
            s += __shfl_xor(s, 4);
            s += __shfl_xor(s, 8);
            if (rl == 0) atomicAdd(&penalty[m], s);
        }
    }
}

__global__ __launch_bounds__(256) void scale_k(float* __restrict__ out,
                                               const float* __restrict__ penalty)
{
    const unsigned cols4 = M_TOT / 4;
    const unsigned total = (unsigned)M_TOT * cols4;
    float4* o4 = reinterpret_cast<float4*>(out);
    const float4* p4 = reinterpret_cast<const float4*>(penalty);
    for (unsigned idx = blockIdx.x * blockDim.x + threadIdx.x; idx < total;
         idx += gridDim.x * blockDim.x) {
        const unsigned n4 = idx % cols4;
        const float4 p = p4[n4];
        float4 v = o4[idx];
        v.x *= rsqrtf(p.x);
        v.y *= rsqrtf(p.y);
        v.z *= rsqrtf(p.z);
        v.w *= rsqrtf(p.w);
        o4[idx] = v;
    }
}

// ---------------- launch ----------------

extern "C" void kernel_launch(void* const* d_in, const int* in_sizes, int n_in,
                              void* d_out, int out_size, void* d_ws, size_t ws_size,
                              hipStream_t stream) {
    const float* A = (const float*)d_in[0];
    const float* B = (const float*)d_in[1];
    float* out     = (float*)d_out;

    const size_t mat_sh = (size_t)M_TOT * C_TOT;
    const size_t sz_ab  = mat_sh * sizeof(short);
    const size_t sz_gb  = (size_t)C_TOT * C_TOT * sizeof(short);
    const size_t sz_p   = (size_t)M_TOT * sizeof(float);
    const size_t sz_gq  = (size_t)C_TOT * C_TOT * sizeof(float);
    const size_t base_need = 3 * sz_ab + sz_gb + sz_p;
    const size_t need_f40  = base_need + 40 * sz_gq;
    const size_t need_f20  = base_need + 20 * sz_gq;
    const size_t need_mid  = 2 * sz_ab + sz_p;

    dim3 grid2(NTILE, NTILE);

    if (ws_size >= need_f20) {
        short* Ab = (short*)d_ws;
        short* Bb = Ab + mat_sh;
        short* Bt = Bb + mat_sh;
        short* Gb = Bt + mat_sh;
        float* P  = (float*)((char*)d_ws + 3 * sz_ab + sz_gb);
        float* Gp = (float*)((char*)d_ws + 3 * sz_ab + sz_gb + sz_p);

        prep<<<500, 256, 0, stream>>>(A, B, Ab, Bb, Bt, P);
        if (ws_size >= need_f40) {
            gemm_G<5><<<dim3(2, 2, 40), 256, 0, stream>>>(Bt, Gp);
            g_reduce<<<64, 256, 0, stream>>>(Gp, Gb, 40);
        } else {
            gemm_G<10><<<dim3(2, 2, 20), 256, 0, stream>>>(Bt, Gp);
            g_reduce<<<64, 256, 0, stream>>>(Gp, Gb, 20);
        }
        penalty_q<<<dim3(NTILE, 4), 256, 0, stream>>>(Ab, Gb, P);
        gemm_out<<<ONM * ONN, 256, 0, stream>>>(Ab, Bb, P, out);
    } else if (ws_size >= need_mid) {
        short* Ab = (short*)d_ws;
        short* Bb = Ab + mat_sh;
        float* P  = (float*)(Bb + mat_sh);

        hipMemsetAsync(P, 0, sz_p, stream);
        convert_ab<<<1600, 256, 0, stream>>>(A, B, Ab, Bb);
        gemm_penalty<<<grid2, dim3(256), 0, stream>>>(Ab, Bb, P);
        gemm_out_plain<<<grid2, dim3(256), 0, stream>>>(Ab, Bb, P, out);
    } else {
        float* penalty = (float*)d_ws;
        hipMemsetAsync(penalty, 0, sz_p, stream);
        corr_gemm<<<grid2, dim3(256), 0, stream>>>(A, B, out, penalty);
        scale_k<<<2048, 256, 0, stream>>>(out, penalty);
    }
}